// Round 1
// baseline (4587.187 us; speedup 1.0000x reference)
//
#include <hip/hip_runtime.h>

#define BATCH 16
#define TLEN 2048
#define CDIM 1024
#define HDIM 128

// ---------------------------------------------------------------------------
// Kernel 1: QKV projection GEMM.  out[m][n] = sum_k x[m][k] * W[k][n]
// M = BATCH*TLEN = 32768, K = CDIM = 1024, N = HDIM = 128.
// blockIdx.x = m-tile (BM=32), blockIdx.y = which W (0=q,1=k,2=v).
// block = 256 threads: thread owns column n = tid&127 and 16 rows.
// ---------------------------------------------------------------------------
__global__ __launch_bounds__(256) void qkv_gemm(
    const float* __restrict__ x,
    const float* __restrict__ Wq, const float* __restrict__ Wk,
    const float* __restrict__ Wv,
    float* __restrict__ q, float* __restrict__ k, float* __restrict__ v)
{
    const float* W;
    float* out;
    if (blockIdx.y == 0)      { W = Wq; out = q; }
    else if (blockIdx.y == 1) { W = Wk; out = k; }
    else                      { W = Wv; out = v; }

    __shared__ float xs[32][36];   // 32 rows x 32 k (+4 pad, keeps 16B align)
    __shared__ float ws[32][HDIM]; // 32 k x 128 n

    const int tid   = threadIdx.x;
    const int m0    = blockIdx.x * 32;
    const int n     = tid & 127;
    const int rg    = tid >> 7;    // 0 or 1
    const int rbase = rg * 16;

    float acc[16];
#pragma unroll
    for (int r = 0; r < 16; ++r) acc[r] = 0.f;

    for (int k0 = 0; k0 < CDIM; k0 += 32) {
        // stage x tile: 32*32 = 1024 floats, 4 per thread, coalesced per row
#pragma unroll
        for (int i = 0; i < 4; ++i) {
            int e = tid + i * 256;
            int r = e >> 5, c = e & 31;
            xs[r][c] = x[(size_t)(m0 + r) * CDIM + k0 + c];
        }
        // stage W tile: 32*128 = 4096 floats, 16 per thread, coalesced
#pragma unroll
        for (int i = 0; i < 16; ++i) {
            int e = tid + i * 256;
            int r = e >> 7, c = e & 127;
            ws[r][c] = W[(size_t)(k0 + r) * HDIM + c];
        }
        __syncthreads();

#pragma unroll
        for (int kk = 0; kk < 32; kk += 4) {
            const float w0 = ws[kk + 0][n];
            const float w1 = ws[kk + 1][n];
            const float w2 = ws[kk + 2][n];
            const float w3 = ws[kk + 3][n];
#pragma unroll
            for (int r = 0; r < 16; ++r) {
                float4 xv = *(const float4*)&xs[rbase + r][kk];
                acc[r] += xv.x * w0 + xv.y * w1 + xv.z * w2 + xv.w * w3;
            }
        }
        __syncthreads();
    }

#pragma unroll
    for (int r = 0; r < 16; ++r)
        out[(size_t)(m0 + rbase + r) * HDIM + n] = acc[r];
}

// ---------------------------------------------------------------------------
// Kernel 2: causal flash attention, one wave (64 lanes) per query row.
// Per 64-wide K/V tile:
//   Phase A: lane j computes s_j = q . K[k0+j] (float4 over H=128)
//   softmax:  wave-reduce max/sum, online rescale
//   Phase B: lanes own h = 2*lane, 2*lane+1; p_j broadcast via __shfl,
//            V reads coalesced (float2 per lane).
// ---------------------------------------------------------------------------
__global__ __launch_bounds__(256) void attn_fwd(
    const float* __restrict__ q, const float* __restrict__ k,
    const float* __restrict__ v, float* __restrict__ out)
{
    const int wave = threadIdx.x >> 6;
    const int lane = threadIdx.x & 63;
    const int row  = blockIdx.x * 4 + wave;       // [0, BATCH*TLEN)
    const int b    = row >> 11;                   // row / TLEN
    const int qi   = row & (TLEN - 1);

    const float* Kb = k + (size_t)b * TLEN * HDIM;
    const float* Vb = v + (size_t)b * TLEN * HDIM;

    __shared__ float qs[4][HDIM];

    // stage this wave's q row into LDS (broadcast source for phase A)
    const float* qrow = q + (size_t)row * HDIM;
    qs[wave][lane]      = qrow[lane];
    qs[wave][lane + 64] = qrow[lane + 64];
    __syncthreads();

    const float4* qs4 = (const float4*)qs[wave];
    const float scale = 0.03125f;  // 1024^-0.5

    float m_run = -INFINITY;
    float l_run = 0.f;
    float2 acc = make_float2(0.f, 0.f);

    const int ntiles = (qi >> 6) + 1;
    for (int t = 0; t < ntiles; ++t) {
        const int k0 = t * 64;
        // ---- Phase A: score for key row (k0 + lane) ----
        const float4* Kr = (const float4*)(Kb + (size_t)(k0 + lane) * HDIM);
        float s = 0.f;
#pragma unroll
        for (int hh = 0; hh < 32; ++hh) {
            float4 qv = qs4[hh];
            float4 kv = Kr[hh];
            s += qv.x * kv.x + qv.y * kv.y + qv.z * kv.z + qv.w * kv.w;
        }
        s *= scale;
        if (k0 + lane > qi) s = -INFINITY;

        // ---- online softmax update ----
        float tm = s;
#pragma unroll
        for (int off = 32; off > 0; off >>= 1)
            tm = fmaxf(tm, __shfl_xor(tm, off));
        const float m_new = fmaxf(m_run, tm);
        const float alpha = __expf(m_run - m_new);   // 0 when m_run = -inf
        const float p     = __expf(s - m_new);       // 0 for masked lanes
        float psum = p;
#pragma unroll
        for (int off = 32; off > 0; off >>= 1)
            psum += __shfl_xor(psum, off);
        l_run = l_run * alpha + psum;
        m_run = m_new;
        acc.x *= alpha;
        acc.y *= alpha;

        // ---- Phase B: acc_h += sum_j p_j * V[k0+j][h], h = 2*lane(+1) ----
        const float2* Vr = (const float2*)(Vb + (size_t)k0 * HDIM) + lane;
#pragma unroll 8
        for (int j = 0; j < 64; ++j) {
            const float pj = __shfl(p, j);
            const float2 vv = Vr[(size_t)j * (HDIM / 2)];
            acc.x += pj * vv.x;
            acc.y += pj * vv.y;
        }
    }

    const float inv_l = 1.f / l_run;
    float2 res = make_float2(acc.x * inv_l, acc.y * inv_l);
    *((float2*)(out + (size_t)row * HDIM) + lane) = res;
}

extern "C" void kernel_launch(void* const* d_in, const int* in_sizes, int n_in,
                              void* d_out, int out_size, void* d_ws, size_t ws_size,
                              hipStream_t stream)
{
    const float* x  = (const float*)d_in[0];
    const float* Wq = (const float*)d_in[1];
    const float* Wk = (const float*)d_in[2];
    const float* Wv = (const float*)d_in[3];
    float* outp = (float*)d_out;

    const size_t per = (size_t)BATCH * TLEN * HDIM;  // 4,194,304 floats
    float* q = (float*)d_ws;
    float* k = q + per;
    float* v = k + per;

    // QKV projections: grid (M/32, 3)
    dim3 g1((BATCH * TLEN) / 32, 3);
    qkv_gemm<<<g1, 256, 0, stream>>>(x, Wq, Wk, Wv, q, k, v);

    // attention: one wave per row, 4 waves per block
    dim3 g2((BATCH * TLEN) / 4);
    attn_fwd<<<g2, 256, 0, stream>>>(q, k, v, outp);
}

// Round 2
// 3827.821 us; speedup vs baseline: 1.1984x; 1.1984x over previous
//
#include <hip/hip_runtime.h>

#define BATCH 16
#define TLEN 2048
#define CDIM 1024
#define HDIM 128

typedef __attribute__((ext_vector_type(8))) short bf16x8;
typedef __attribute__((ext_vector_type(4))) float f32x4;

static __device__ __forceinline__ unsigned short f2bf(float f) {
    union { float f; unsigned u; } x; x.f = f;
    unsigned r = x.u + 0x7fffu + ((x.u >> 16) & 1u);   // round-to-nearest-even
    return (unsigned short)(r >> 16);
}

// ---------------------------------------------------------------------------
// Kernel 1: QKV projection GEMM (fp32 compute, bf16 outputs).
// q is pre-scaled by 1024^-0.5 = 1/32.  v is stored TRANSPOSED: vt[b][h][t].
// ---------------------------------------------------------------------------
__global__ __launch_bounds__(256) void qkv_gemm(
    const float* __restrict__ x,
    const float* __restrict__ Wq, const float* __restrict__ Wk,
    const float* __restrict__ Wv,
    unsigned short* __restrict__ qb, unsigned short* __restrict__ kb,
    unsigned short* __restrict__ vtb)
{
    const float* W;
    if (blockIdx.y == 0)      W = Wq;
    else if (blockIdx.y == 1) W = Wk;
    else                      W = Wv;

    __shared__ float xs[32][36];
    __shared__ float ws[32][HDIM];

    const int tid   = threadIdx.x;
    const int m0    = blockIdx.x * 32;
    const int n     = tid & 127;
    const int rg    = tid >> 7;
    const int rbase = rg * 16;

    float acc[16];
#pragma unroll
    for (int r = 0; r < 16; ++r) acc[r] = 0.f;

    for (int k0 = 0; k0 < CDIM; k0 += 32) {
#pragma unroll
        for (int i = 0; i < 4; ++i) {
            int e = tid + i * 256;
            int r = e >> 5, c = e & 31;
            xs[r][c] = x[(size_t)(m0 + r) * CDIM + k0 + c];
        }
#pragma unroll
        for (int i = 0; i < 16; ++i) {
            int e = tid + i * 256;
            int r = e >> 7, c = e & 127;
            ws[r][c] = W[(size_t)(k0 + r) * HDIM + c];
        }
        __syncthreads();

#pragma unroll
        for (int kk = 0; kk < 32; kk += 4) {
            const float w0 = ws[kk + 0][n];
            const float w1 = ws[kk + 1][n];
            const float w2 = ws[kk + 2][n];
            const float w3 = ws[kk + 3][n];
#pragma unroll
            for (int r = 0; r < 16; ++r) {
                float4 xv = *(const float4*)&xs[rbase + r][kk];
                acc[r] += xv.x * w0 + xv.y * w1 + xv.z * w2 + xv.w * w3;
            }
        }
        __syncthreads();
    }

    if (blockIdx.y == 0) {
#pragma unroll
        for (int r = 0; r < 16; ++r)
            qb[(size_t)(m0 + rbase + r) * HDIM + n] = f2bf(acc[r] * 0.03125f);
    } else if (blockIdx.y == 1) {
#pragma unroll
        for (int r = 0; r < 16; ++r)
            kb[(size_t)(m0 + rbase + r) * HDIM + n] = f2bf(acc[r]);
    } else {
#pragma unroll
        for (int r = 0; r < 16; ++r) {
            int m = m0 + rbase + r;
            int b = m >> 11, t = m & (TLEN - 1);
            vtb[((size_t)b * HDIM + n) * TLEN + t] = f2bf(acc[r]);
        }
    }
}

// ---------------------------------------------------------------------------
// Kernel 2: causal flash attention, bf16 MFMA (16x16x32).
// One wave (64 threads) per 16 query rows. KV tile = 64 keys.
// S = Q.K^T via mfma(A=Qfrag, B=Kfrag) -> C layout [row=4g+r][col=key=c].
// Softmax online per row (shfl_xor 1,2,4,8 within the 16-lane group).
// P goes C-layout -> LDS (XOR-swizzled bf16) -> A-layout frags for PV.
// PV: O += P.V with V read from vt[b][h][t] (contiguous B-fragments).
// ---------------------------------------------------------------------------
__global__ __launch_bounds__(64) void attn_fwd(
    const short* __restrict__ qb, const short* __restrict__ kb,
    const short* __restrict__ vtb, float* __restrict__ out)
{
    __shared__ unsigned short plds[2][16 * 64];   // [buf][row][key], swizzled

    const int lane = threadIdx.x;
    const int g = lane >> 4, c = lane & 15;

    const int qt = blockIdx.x & 127;     // 16-row q tile within batch
    const int b  = blockIdx.x >> 7;
    const int q0 = qt * 16;

    const short* Kb  = kb  + (size_t)b * TLEN * HDIM;
    const short* Vtb = vtb + (size_t)b * HDIM * TLEN;

    bf16x8 qf[4];
#pragma unroll
    for (int ks = 0; ks < 4; ++ks)
        qf[ks] = *(const bf16x8*)(qb + ((size_t)b * TLEN + q0 + c) * HDIM + ks * 32 + g * 8);

    f32x4 oacc[8];
#pragma unroll
    for (int i = 0; i < 8; ++i) oacc[i] = (f32x4){0.f, 0.f, 0.f, 0.f};
    float m_r[4] = {-INFINITY, -INFINITY, -INFINITY, -INFINITY};
    float l_r[4] = {0.f, 0.f, 0.f, 0.f};

    const int dt   = qt >> 2;   // diagonal KV-tile index
    const int dsub = qt & 3;    // diagonal 16-key subtile within it

    for (int t = 0; t <= dt; ++t) {
        const int kv0 = t * 64;
        const bool diag = (t == dt);
        const int nst = diag ? (dsub + 1) : 4;

        // ---- QK^T ----
        f32x4 sacc[4];
#pragma unroll
        for (int st = 0; st < 4; ++st) sacc[st] = (f32x4){0.f, 0.f, 0.f, 0.f};
        for (int st = 0; st < nst; ++st) {
            const short* Krow = Kb + (size_t)(kv0 + st * 16 + c) * HDIM + g * 8;
#pragma unroll
            for (int ks = 0; ks < 4; ++ks) {
                bf16x8 kf = *(const bf16x8*)(Krow + ks * 32);
                sacc[st] = __builtin_amdgcn_mfma_f32_16x16x32_bf16(qf[ks], kf, sacc[st], 0, 0, 0);
            }
        }

        // ---- online softmax ----
        float sv[4][4];
#pragma unroll
        for (int st = 0; st < 4; ++st)
#pragma unroll
            for (int r = 0; r < 4; ++r)
                sv[st][r] = (st < nst) ? sacc[st][r] : -INFINITY;
        if (diag) {
#pragma unroll
            for (int st = 0; st < 4; ++st)
#pragma unroll
                for (int r = 0; r < 4; ++r)
                    if (kv0 + st * 16 + c > q0 + 4 * g + r) sv[st][r] = -INFINITY;
        }

        float rm[4], mnew[4], alpha[4], rs[4];
#pragma unroll
        for (int r = 0; r < 4; ++r)
            rm[r] = fmaxf(fmaxf(sv[0][r], sv[1][r]), fmaxf(sv[2][r], sv[3][r]));
#pragma unroll
        for (int off = 1; off <= 8; off <<= 1)
#pragma unroll
            for (int r = 0; r < 4; ++r)
                rm[r] = fmaxf(rm[r], __shfl_xor(rm[r], off));
#pragma unroll
        for (int r = 0; r < 4; ++r) {
            mnew[r]  = fmaxf(m_r[r], rm[r]);
            alpha[r] = __expf(m_r[r] - mnew[r]);   // 0 when m_r = -inf
            rs[r]    = 0.f;
        }

        const int buf = t & 1;
#pragma unroll
        for (int st = 0; st < 4; ++st)
#pragma unroll
            for (int r = 0; r < 4; ++r) {
                float p = __expf(sv[st][r] - mnew[r]);   // masked -> 0
                rs[r] += p;
                int row = 4 * g + r;
                int off = row * 128 + (st * 16 + c) * 2;
                off ^= (row & 7) << 4;
                *(unsigned short*)((char*)plds[buf] + off) = f2bf(p);
            }
#pragma unroll
        for (int off = 1; off <= 8; off <<= 1)
#pragma unroll
            for (int r = 0; r < 4; ++r)
                rs[r] += __shfl_xor(rs[r], off);
#pragma unroll
        for (int r = 0; r < 4; ++r) {
            l_r[r] = l_r[r] * alpha[r] + rs[r];
            m_r[r] = mnew[r];
        }
#pragma unroll
        for (int ht = 0; ht < 8; ++ht) {
            oacc[ht][0] *= alpha[0]; oacc[ht][1] *= alpha[1];
            oacc[ht][2] *= alpha[2]; oacc[ht][3] *= alpha[3];
        }

        __syncthreads();   // P writes visible to whole wave

        // ---- PV ----
        const int nks2 = diag ? ((dsub < 2) ? 1 : 2) : 2;
        bf16x8 pa[2];
        for (int ks2 = 0; ks2 < nks2; ++ks2) {
            int off = c * 128 + ks2 * 64 + g * 16;
            off ^= (c & 7) << 4;
            pa[ks2] = *(const bf16x8*)((char*)plds[buf] + off);
        }
#pragma unroll
        for (int ht = 0; ht < 8; ++ht) {
            const short* Vrow = Vtb + (size_t)(ht * 16 + c) * TLEN + kv0 + g * 8;
            for (int ks2 = 0; ks2 < nks2; ++ks2) {
                bf16x8 vf = *(const bf16x8*)(Vrow + ks2 * 32);
                oacc[ht] = __builtin_amdgcn_mfma_f32_16x16x32_bf16(pa[ks2], vf, oacc[ht], 0, 0, 0);
            }
        }
    }

    float inv[4];
#pragma unroll
    for (int r = 0; r < 4; ++r) inv[r] = 1.f / l_r[r];
    float* Ob = out + ((size_t)b * TLEN + q0) * HDIM;
#pragma unroll
    for (int ht = 0; ht < 8; ++ht)
#pragma unroll
        for (int r = 0; r < 4; ++r)
            Ob[(size_t)(4 * g + r) * HDIM + ht * 16 + c] = oacc[ht][r] * inv[r];
}

extern "C" void kernel_launch(void* const* d_in, const int* in_sizes, int n_in,
                              void* d_out, int out_size, void* d_ws, size_t ws_size,
                              hipStream_t stream)
{
    const float* x  = (const float*)d_in[0];
    const float* Wq = (const float*)d_in[1];
    const float* Wk = (const float*)d_in[2];
    const float* Wv = (const float*)d_in[3];
    float* outp = (float*)d_out;

    const size_t per = (size_t)BATCH * TLEN * HDIM;  // 4,194,304 elements
    unsigned short* qb  = (unsigned short*)d_ws;
    unsigned short* kb  = qb + per;
    unsigned short* vtb = kb + per;

    dim3 g1((BATCH * TLEN) / 32, 3);
    qkv_gemm<<<g1, 256, 0, stream>>>(x, Wq, Wk, Wv, qb, kb, vtb);

    dim3 g2(BATCH * (TLEN / 16));
    attn_fwd<<<g2, 64, 0, stream>>>((const short*)qb, (const short*)kb,
                                    (const short*)vtb, outp);
}

// Round 3
// 790.348 us; speedup vs baseline: 5.8040x; 4.8432x over previous
//
#include <hip/hip_runtime.h>
#include <hip/hip_bf16.h>

#define BATCH 16
#define TLEN 2048
#define CDIM 1024
#define HDIM 128

typedef __attribute__((ext_vector_type(8))) short bf16x8;
typedef __attribute__((ext_vector_type(4))) float f32x4;
typedef __attribute__((ext_vector_type(4))) unsigned short u16x4;

static __device__ __forceinline__ unsigned short f2bf(float f) {
    __hip_bfloat16 h = __float2bfloat16(f);
    return *(unsigned short*)&h;
}

// ---------------------------------------------------------------------------
// Prep: pack Wq|Wk|Wv into transposed bf16  wtb[(which*128+n)*1024 + k].
// ---------------------------------------------------------------------------
__global__ __launch_bounds__(256) void pack_w(
    const float* __restrict__ Wq, const float* __restrict__ Wk,
    const float* __restrict__ Wv, unsigned short* __restrict__ wtb)
{
    const int which = blockIdx.y;
    const float* W = (which == 0) ? Wq : (which == 1) ? Wk : Wv;
    const int n = blockIdx.x >> 2;                       // 0..127
    const int k = (blockIdx.x & 3) * 256 + threadIdx.x;  // 0..1023
    wtb[((size_t)which * 128 + n) * 1024 + k] = f2bf(W[(size_t)k * 128 + n]);
}

// ---------------------------------------------------------------------------
// Kernel 1: QKV projection, bf16 MFMA.  C = x @ W  (x cast to bf16 in-reg).
// 128x128 tile, BK=64, 4 waves (2x2 of 64x64 each), XOR-swizzled LDS.
// blockIdx.y: 0 -> qb (scaled by 1/32), 1 -> kb, 2 -> vtb (transposed [b][h][t]).
// ---------------------------------------------------------------------------
__global__ __launch_bounds__(256) void qkv_mfma(
    const float* __restrict__ x, const unsigned short* __restrict__ wtb,
    unsigned short* __restrict__ qb, unsigned short* __restrict__ kb,
    unsigned short* __restrict__ vtb)
{
    __shared__ unsigned short As[128 * 64];   // [row m][k], swizzled
    __shared__ unsigned short Bs[128 * 64];   // [row n][k], swizzled

    const int tid  = threadIdx.x;
    const int lane = tid & 63, wid = tid >> 6;
    const int wm = wid >> 1, wn = wid & 1;
    const int c = lane & 15, g = lane >> 4;
    const int m0 = blockIdx.x * 128;
    const int nt = blockIdx.y;
    const unsigned short* Wp = wtb + (size_t)nt * 128 * 1024;

    f32x4 acc[4][4];
#pragma unroll
    for (int i = 0; i < 4; ++i)
#pragma unroll
        for (int j = 0; j < 4; ++j) acc[i][j] = (f32x4){0.f, 0.f, 0.f, 0.f};

    bf16x8 av[4], bv[4];

    // ---- prologue: load & stage tile k0 = 0 ----
#pragma unroll
    for (int i = 0; i < 4; ++i) {
        const int j = tid + i * 256, row = j >> 3, ch = j & 7;
        const float* src = x + (size_t)(m0 + row) * CDIM + ch * 8;
        float4 f0 = *(const float4*)src, f1 = *(const float4*)(src + 4);
        bf16x8 t;
        t[0]=f2bf(f0.x); t[1]=f2bf(f0.y); t[2]=f2bf(f0.z); t[3]=f2bf(f0.w);
        t[4]=f2bf(f1.x); t[5]=f2bf(f1.y); t[6]=f2bf(f1.z); t[7]=f2bf(f1.w);
        av[i] = t;
        bv[i] = *(const bf16x8*)(Wp + (size_t)row * 1024 + ch * 8);
    }
#pragma unroll
    for (int i = 0; i < 4; ++i) {
        const int j = tid + i * 256, row = j >> 3, ch = j & 7;
        const int off = row * 128 + ((ch * 16) ^ ((row & 7) << 4));
        *(bf16x8*)((char*)As + off) = av[i];
        *(bf16x8*)((char*)Bs + off) = bv[i];
    }
    __syncthreads();

#pragma unroll 1
    for (int kt = 0; kt < 16; ++kt) {
        // ---- issue next tile's global loads early (hide under MFMA) ----
        if (kt < 15) {
            const int k0 = (kt + 1) * 64;
#pragma unroll
            for (int i = 0; i < 4; ++i) {
                const int j = tid + i * 256, row = j >> 3, ch = j & 7;
                const float* src = x + (size_t)(m0 + row) * CDIM + k0 + ch * 8;
                float4 f0 = *(const float4*)src, f1 = *(const float4*)(src + 4);
                bf16x8 t;
                t[0]=f2bf(f0.x); t[1]=f2bf(f0.y); t[2]=f2bf(f0.z); t[3]=f2bf(f0.w);
                t[4]=f2bf(f1.x); t[5]=f2bf(f1.y); t[6]=f2bf(f1.z); t[7]=f2bf(f1.w);
                av[i] = t;
                bv[i] = *(const bf16x8*)(Wp + (size_t)row * 1024 + k0 + ch * 8);
            }
        }

        // ---- compute current tile ----
#pragma unroll
        for (int ks = 0; ks < 2; ++ks) {
            bf16x8 af[4], bf[4];
#pragma unroll
            for (int mf = 0; mf < 4; ++mf) {
                const int row = wm * 64 + mf * 16 + c;
                const int off = row * 128 + ((ks * 64 + g * 16) ^ ((row & 7) << 4));
                af[mf] = *(const bf16x8*)((char*)As + off);
            }
#pragma unroll
            for (int nf = 0; nf < 4; ++nf) {
                const int row = wn * 64 + nf * 16 + c;
                const int off = row * 128 + ((ks * 64 + g * 16) ^ ((row & 7) << 4));
                bf[nf] = *(const bf16x8*)((char*)Bs + off);
            }
#pragma unroll
            for (int mf = 0; mf < 4; ++mf)
#pragma unroll
                for (int nf = 0; nf < 4; ++nf)
                    acc[mf][nf] = __builtin_amdgcn_mfma_f32_16x16x32_bf16(
                        af[mf], bf[nf], acc[mf][nf], 0, 0, 0);
        }

        if (kt < 15) {
            __syncthreads();
#pragma unroll
            for (int i = 0; i < 4; ++i) {
                const int j = tid + i * 256, row = j >> 3, ch = j & 7;
                const int off = row * 128 + ((ch * 16) ^ ((row & 7) << 4));
                *(bf16x8*)((char*)As + off) = av[i];
                *(bf16x8*)((char*)Bs + off) = bv[i];
            }
            __syncthreads();
        }
    }

    // ---- epilogue ----
    const int mb = m0 + wm * 64, nb = wn * 64;
    if (nt == 0) {
#pragma unroll
        for (int mf = 0; mf < 4; ++mf)
#pragma unroll
            for (int nf = 0; nf < 4; ++nf)
#pragma unroll
                for (int r = 0; r < 4; ++r) {
                    const int m = mb + mf * 16 + g * 4 + r;
                    const int n = nb + nf * 16 + c;
                    qb[(size_t)m * HDIM + n] = f2bf(acc[mf][nf][r] * 0.03125f);
                }
    } else if (nt == 1) {
#pragma unroll
        for (int mf = 0; mf < 4; ++mf)
#pragma unroll
            for (int nf = 0; nf < 4; ++nf)
#pragma unroll
                for (int r = 0; r < 4; ++r) {
                    const int m = mb + mf * 16 + g * 4 + r;
                    const int n = nb + nf * 16 + c;
                    kb[(size_t)m * HDIM + n] = f2bf(acc[mf][nf][r]);
                }
    } else {
#pragma unroll
        for (int mf = 0; mf < 4; ++mf)
#pragma unroll
            for (int nf = 0; nf < 4; ++nf) {
                const int m = mb + mf * 16 + g * 4;
                const int b = m >> 11, t = m & (TLEN - 1);
                const int n = nb + nf * 16 + c;
                u16x4 o;
                o[0] = f2bf(acc[mf][nf][0]); o[1] = f2bf(acc[mf][nf][1]);
                o[2] = f2bf(acc[mf][nf][2]); o[3] = f2bf(acc[mf][nf][3]);
                *(u16x4*)(vtb + ((size_t)b * HDIM + n) * TLEN + t) = o;
            }
    }
}

// ---------------------------------------------------------------------------
// Kernel 2: causal flash attention, bf16 MFMA (16x16x32).
// 4 independent waves per block, each owns one 16-row q tile. KV tile = 64.
// Heavy (high-q) tiles scheduled first via reversed tile id.
// ---------------------------------------------------------------------------
__global__ __launch_bounds__(256) void attn_fwd(
    const short* __restrict__ qb, const short* __restrict__ kb,
    const short* __restrict__ vtb, float* __restrict__ out)
{
    __shared__ unsigned short plds[4][2][16 * 64];   // per-wave [buf][row][key]

    const int wid  = threadIdx.x >> 6;
    const int lane = threadIdx.x & 63;
    const int g = lane >> 4, c = lane & 15;

    const int rev = (BATCH * TLEN / 16 - 1) - (blockIdx.x * 4 + wid);
    const int qt = rev & 127;
    const int b  = rev >> 7;
    const int q0 = qt * 16;

    const short* Kb  = kb  + (size_t)b * TLEN * HDIM;
    const short* Vtb = vtb + (size_t)b * HDIM * TLEN;

    bf16x8 qf[4];
#pragma unroll
    for (int ks = 0; ks < 4; ++ks)
        qf[ks] = *(const bf16x8*)(qb + ((size_t)b * TLEN + q0 + c) * HDIM + ks * 32 + g * 8);

    f32x4 oacc[8];
#pragma unroll
    for (int i = 0; i < 8; ++i) oacc[i] = (f32x4){0.f, 0.f, 0.f, 0.f};
    float m_r[4] = {-INFINITY, -INFINITY, -INFINITY, -INFINITY};
    float l_r[4] = {0.f, 0.f, 0.f, 0.f};

    const int dt   = qt >> 2;
    const int dsub = qt & 3;

    for (int t = 0; t <= dt; ++t) {
        const int kv0 = t * 64;
        const bool diag = (t == dt);
        const int nst = diag ? (dsub + 1) : 4;

        // ---- QK^T ----
        f32x4 sacc[4];
#pragma unroll
        for (int st = 0; st < 4; ++st) sacc[st] = (f32x4){0.f, 0.f, 0.f, 0.f};
        for (int st = 0; st < nst; ++st) {
            const short* Krow = Kb + (size_t)(kv0 + st * 16 + c) * HDIM + g * 8;
#pragma unroll
            for (int ks = 0; ks < 4; ++ks) {
                bf16x8 kf = *(const bf16x8*)(Krow + ks * 32);
                sacc[st] = __builtin_amdgcn_mfma_f32_16x16x32_bf16(qf[ks], kf, sacc[st], 0, 0, 0);
            }
        }

        // ---- online softmax ----
        float sv[4][4];
#pragma unroll
        for (int st = 0; st < 4; ++st)
#pragma unroll
            for (int r = 0; r < 4; ++r)
                sv[st][r] = (st < nst) ? sacc[st][r] : -INFINITY;
        if (diag) {
#pragma unroll
            for (int st = 0; st < 4; ++st)
#pragma unroll
                for (int r = 0; r < 4; ++r)
                    if (kv0 + st * 16 + c > q0 + 4 * g + r) sv[st][r] = -INFINITY;
        }

        float rm[4], mnew[4], alpha[4], rs[4];
#pragma unroll
        for (int r = 0; r < 4; ++r)
            rm[r] = fmaxf(fmaxf(sv[0][r], sv[1][r]), fmaxf(sv[2][r], sv[3][r]));
#pragma unroll
        for (int off = 1; off <= 8; off <<= 1)
#pragma unroll
            for (int r = 0; r < 4; ++r)
                rm[r] = fmaxf(rm[r], __shfl_xor(rm[r], off));
#pragma unroll
        for (int r = 0; r < 4; ++r) {
            mnew[r]  = fmaxf(m_r[r], rm[r]);
            alpha[r] = __expf(m_r[r] - mnew[r]);
            rs[r]    = 0.f;
        }

        const int buf = t & 1;
#pragma unroll
        for (int st = 0; st < 4; ++st)
#pragma unroll
            for (int r = 0; r < 4; ++r) {
                float p = __expf(sv[st][r] - mnew[r]);
                rs[r] += p;
                int row = 4 * g + r;
                int off = row * 128 + (st * 16 + c) * 2;
                off ^= (row & 7) << 4;
                *(unsigned short*)((char*)plds[wid][buf] + off) = f2bf(p);
            }
#pragma unroll
        for (int off = 1; off <= 8; off <<= 1)
#pragma unroll
            for (int r = 0; r < 4; ++r)
                rs[r] += __shfl_xor(rs[r], off);
#pragma unroll
        for (int r = 0; r < 4; ++r) {
            l_r[r] = l_r[r] * alpha[r] + rs[r];
            m_r[r] = mnew[r];
        }
#pragma unroll
        for (int ht = 0; ht < 8; ++ht) {
            oacc[ht][0] *= alpha[0]; oacc[ht][1] *= alpha[1];
            oacc[ht][2] *= alpha[2]; oacc[ht][3] *= alpha[3];
        }

        asm volatile("s_waitcnt lgkmcnt(0)" ::: "memory");  // in-wave P visibility

        // ---- PV ----
        const int nks2 = diag ? ((dsub < 2) ? 1 : 2) : 2;
        bf16x8 pa[2];
        for (int ks2 = 0; ks2 < nks2; ++ks2) {
            int off = c * 128 + ks2 * 64 + g * 16;
            off ^= (c & 7) << 4;
            pa[ks2] = *(const bf16x8*)((char*)plds[wid][buf] + off);
        }
#pragma unroll
        for (int ht = 0; ht < 8; ++ht) {
            const short* Vrow = Vtb + (size_t)(ht * 16 + c) * TLEN + kv0 + g * 8;
            for (int ks2 = 0; ks2 < nks2; ++ks2) {
                bf16x8 vf = *(const bf16x8*)(Vrow + ks2 * 32);
                oacc[ht] = __builtin_amdgcn_mfma_f32_16x16x32_bf16(pa[ks2], vf, oacc[ht], 0, 0, 0);
            }
        }
    }

    float inv[4];
#pragma unroll
    for (int r = 0; r < 4; ++r) inv[r] = 1.f / l_r[r];
    float* Ob = out + ((size_t)b * TLEN + q0) * HDIM;
#pragma unroll
    for (int ht = 0; ht < 8; ++ht)
#pragma unroll
        for (int r = 0; r < 4; ++r)
            Ob[(size_t)(4 * g + r) * HDIM + ht * 16 + c] = oacc[ht][r] * inv[r];
}

extern "C" void kernel_launch(void* const* d_in, const int* in_sizes, int n_in,
                              void* d_out, int out_size, void* d_ws, size_t ws_size,
                              hipStream_t stream)
{
    const float* x  = (const float*)d_in[0];
    const float* Wq = (const float*)d_in[1];
    const float* Wk = (const float*)d_in[2];
    const float* Wv = (const float*)d_in[3];
    float* outp = (float*)d_out;

    const size_t per = (size_t)BATCH * TLEN * HDIM;  // 4,194,304 elements
    unsigned short* qb  = (unsigned short*)d_ws;
    unsigned short* kb  = qb + per;
    unsigned short* vtb = kb + per;
    unsigned short* wtb = vtb + per;                 // 384*1024 bf16

    dim3 gw(512, 3);
    pack_w<<<gw, 256, 0, stream>>>(Wq, Wk, Wv, wtb);

    dim3 g1((BATCH * TLEN) / 128, 3);
    qkv_mfma<<<g1, 256, 0, stream>>>(x, wtb, qb, kb, vtb);

    dim3 g2(BATCH * (TLEN / 16) / 4);
    attn_fwd<<<g2, 256, 0, stream>>>((const short*)qb, (const short*)kb,
                                     (const short*)vtb, outp);
}

// Round 4
// 348.611 us; speedup vs baseline: 13.1585x; 2.2671x over previous
//
#include <hip/hip_runtime.h>
#include <hip/hip_bf16.h>

#define BATCH 16
#define TLEN 2048
#define CDIM 1024
#define HDIM 128

typedef __attribute__((ext_vector_type(8))) short bf16x8;
typedef __attribute__((ext_vector_type(4))) float f32x4;
typedef __attribute__((ext_vector_type(4))) unsigned short u16x4;

static __device__ __forceinline__ unsigned short f2bf(float f) {
    __hip_bfloat16 h = __float2bfloat16(f);
    return *(unsigned short*)&h;
}

// ---------------------------------------------------------------------------
// Prep: pack Wq|Wk|Wv into transposed bf16  wtb[(which*128+n)*1024 + k].
// ---------------------------------------------------------------------------
__global__ __launch_bounds__(256) void pack_w(
    const float* __restrict__ Wq, const float* __restrict__ Wk,
    const float* __restrict__ Wv, unsigned short* __restrict__ wtb)
{
    const int which = blockIdx.y;
    const float* W = (which == 0) ? Wq : (which == 1) ? Wk : Wv;
    const int n = blockIdx.x >> 2;
    const int k = (blockIdx.x & 3) * 256 + threadIdx.x;
    wtb[((size_t)which * 128 + n) * 1024 + k] = f2bf(W[(size_t)k * 128 + n]);
}

// ---------------------------------------------------------------------------
// Kernel 1: QKV projection, bf16 MFMA (unchanged from round 3).
// ---------------------------------------------------------------------------
__global__ __launch_bounds__(256) void qkv_mfma(
    const float* __restrict__ x, const unsigned short* __restrict__ wtb,
    unsigned short* __restrict__ qb, unsigned short* __restrict__ kb,
    unsigned short* __restrict__ vtb)
{
    __shared__ unsigned short As[128 * 64];
    __shared__ unsigned short Bs[128 * 64];

    const int tid  = threadIdx.x;
    const int lane = tid & 63, wid = tid >> 6;
    const int wm = wid >> 1, wn = wid & 1;
    const int c = lane & 15, g = lane >> 4;
    const int m0 = blockIdx.x * 128;
    const int nt = blockIdx.y;
    const unsigned short* Wp = wtb + (size_t)nt * 128 * 1024;

    f32x4 acc[4][4];
#pragma unroll
    for (int i = 0; i < 4; ++i)
#pragma unroll
        for (int j = 0; j < 4; ++j) acc[i][j] = (f32x4){0.f, 0.f, 0.f, 0.f};

    bf16x8 av[4], bv[4];

#pragma unroll
    for (int i = 0; i < 4; ++i) {
        const int j = tid + i * 256, row = j >> 3, ch = j & 7;
        const float* src = x + (size_t)(m0 + row) * CDIM + ch * 8;
        float4 f0 = *(const float4*)src, f1 = *(const float4*)(src + 4);
        bf16x8 t;
        t[0]=f2bf(f0.x); t[1]=f2bf(f0.y); t[2]=f2bf(f0.z); t[3]=f2bf(f0.w);
        t[4]=f2bf(f1.x); t[5]=f2bf(f1.y); t[6]=f2bf(f1.z); t[7]=f2bf(f1.w);
        av[i] = t;
        bv[i] = *(const bf16x8*)(Wp + (size_t)row * 1024 + ch * 8);
    }
#pragma unroll
    for (int i = 0; i < 4; ++i) {
        const int j = tid + i * 256, row = j >> 3, ch = j & 7;
        const int off = row * 128 + ((ch * 16) ^ ((row & 7) << 4));
        *(bf16x8*)((char*)As + off) = av[i];
        *(bf16x8*)((char*)Bs + off) = bv[i];
    }
    __syncthreads();

#pragma unroll 1
    for (int kt = 0; kt < 16; ++kt) {
        if (kt < 15) {
            const int k0 = (kt + 1) * 64;
#pragma unroll
            for (int i = 0; i < 4; ++i) {
                const int j = tid + i * 256, row = j >> 3, ch = j & 7;
                const float* src = x + (size_t)(m0 + row) * CDIM + k0 + ch * 8;
                float4 f0 = *(const float4*)src, f1 = *(const float4*)(src + 4);
                bf16x8 t;
                t[0]=f2bf(f0.x); t[1]=f2bf(f0.y); t[2]=f2bf(f0.z); t[3]=f2bf(f0.w);
                t[4]=f2bf(f1.x); t[5]=f2bf(f1.y); t[6]=f2bf(f1.z); t[7]=f2bf(f1.w);
                av[i] = t;
                bv[i] = *(const bf16x8*)(Wp + (size_t)row * 1024 + k0 + ch * 8);
            }
        }

#pragma unroll
        for (int ks = 0; ks < 2; ++ks) {
            bf16x8 af[4], bf[4];
#pragma unroll
            for (int mf = 0; mf < 4; ++mf) {
                const int row = wm * 64 + mf * 16 + c;
                const int off = row * 128 + ((ks * 64 + g * 16) ^ ((row & 7) << 4));
                af[mf] = *(const bf16x8*)((char*)As + off);
            }
#pragma unroll
            for (int nf = 0; nf < 4; ++nf) {
                const int row = wn * 64 + nf * 16 + c;
                const int off = row * 128 + ((ks * 64 + g * 16) ^ ((row & 7) << 4));
                bf[nf] = *(const bf16x8*)((char*)Bs + off);
            }
#pragma unroll
            for (int mf = 0; mf < 4; ++mf)
#pragma unroll
                for (int nf = 0; nf < 4; ++nf)
                    acc[mf][nf] = __builtin_amdgcn_mfma_f32_16x16x32_bf16(
                        af[mf], bf[nf], acc[mf][nf], 0, 0, 0);
        }

        if (kt < 15) {
            __syncthreads();
#pragma unroll
            for (int i = 0; i < 4; ++i) {
                const int j = tid + i * 256, row = j >> 3, ch = j & 7;
                const int off = row * 128 + ((ch * 16) ^ ((row & 7) << 4));
                *(bf16x8*)((char*)As + off) = av[i];
                *(bf16x8*)((char*)Bs + off) = bv[i];
            }
            __syncthreads();
        }
    }

    const int mb = m0 + wm * 64, nb = wn * 64;
    if (nt == 0) {
#pragma unroll
        for (int mf = 0; mf < 4; ++mf)
#pragma unroll
            for (int nf = 0; nf < 4; ++nf)
#pragma unroll
                for (int r = 0; r < 4; ++r) {
                    const int m = mb + mf * 16 + g * 4 + r;
                    const int n = nb + nf * 16 + c;
                    qb[(size_t)m * HDIM + n] = f2bf(acc[mf][nf][r] * 0.03125f);
                }
    } else if (nt == 1) {
#pragma unroll
        for (int mf = 0; mf < 4; ++mf)
#pragma unroll
            for (int nf = 0; nf < 4; ++nf)
#pragma unroll
                for (int r = 0; r < 4; ++r) {
                    const int m = mb + mf * 16 + g * 4 + r;
                    const int n = nb + nf * 16 + c;
                    kb[(size_t)m * HDIM + n] = f2bf(acc[mf][nf][r]);
                }
    } else {
#pragma unroll
        for (int mf = 0; mf < 4; ++mf)
#pragma unroll
            for (int nf = 0; nf < 4; ++nf) {
                const int m = mb + mf * 16 + g * 4;
                const int b = m >> 11, t = m & (TLEN - 1);
                const int n = nb + nf * 16 + c;
                u16x4 o;
                o[0] = f2bf(acc[mf][nf][0]); o[1] = f2bf(acc[mf][nf][1]);
                o[2] = f2bf(acc[mf][nf][2]); o[3] = f2bf(acc[mf][nf][3]);
                *(u16x4*)(vtb + ((size_t)b * HDIM + n) * TLEN + t) = o;
            }
    }
}

// ---------------------------------------------------------------------------
// Kernel 2a: flash-attention partials (KV-split for load balance).
// Task = (b, qc [64 q rows], kc [256 keys]); grid (8,32,16), inactive blocks
// exit. 4 waves/block, wave w owns q rows [64*qc+16*w, +16).
// Non-diag tasks: 4 full KV tiles, compile-time unrolled, no masking.
// Stores unnormalized O (f32) + per-row m, l.
// ---------------------------------------------------------------------------
__global__ __launch_bounds__(256) void attn_partial(
    const short* __restrict__ qb, const short* __restrict__ kb,
    const short* __restrict__ vtb,
    float* __restrict__ Opart, float* __restrict__ mpart,
    float* __restrict__ lpart)
{
    const int kc = blockIdx.x;
    const int qc = blockIdx.y;
    const int b  = blockIdx.z;
    const int gq = qc >> 2;
    if (kc > gq) return;
    const bool isdiag = (kc == gq);

    __shared__ unsigned short plds[4][2][16 * 64];

    const int wid  = threadIdx.x >> 6;
    const int lane = threadIdx.x & 63;
    const int g = lane >> 4, c = lane & 15;
    const int q0 = qc * 64 + wid * 16;
    const int kv_base = kc * 256;
    const int pidx = b * 144 + (gq + 1) * (qc - 2 * gq) + kc;

    const short* Kb  = kb  + (size_t)b * TLEN * HDIM;
    const short* Vtb = vtb + (size_t)b * HDIM * TLEN;

    bf16x8 qf[4];
#pragma unroll
    for (int ks = 0; ks < 4; ++ks)
        qf[ks] = *(const bf16x8*)(qb + ((size_t)b * TLEN + q0 + c) * HDIM + ks * 32 + g * 8);

    f32x4 oacc[8];
#pragma unroll
    for (int i = 0; i < 8; ++i) oacc[i] = (f32x4){0.f, 0.f, 0.f, 0.f};
    float m_r[4] = {-INFINITY, -INFINITY, -INFINITY, -INFINITY};
    float l_r[4] = {0.f, 0.f, 0.f, 0.f};
    int tcnt = 0;

    auto tile = [&](int kv0, int nst, bool dmask) {
        f32x4 sacc[4];
#pragma unroll
        for (int st = 0; st < 4; ++st) sacc[st] = (f32x4){0.f, 0.f, 0.f, 0.f};
        for (int st = 0; st < nst; ++st) {
            const short* Krow = Kb + (size_t)(kv0 + st * 16 + c) * HDIM + g * 8;
#pragma unroll
            for (int ks = 0; ks < 4; ++ks) {
                bf16x8 kf = *(const bf16x8*)(Krow + ks * 32);
                sacc[st] = __builtin_amdgcn_mfma_f32_16x16x32_bf16(qf[ks], kf, sacc[st], 0, 0, 0);
            }
        }

        float sv[4][4];
#pragma unroll
        for (int st = 0; st < 4; ++st)
#pragma unroll
            for (int r = 0; r < 4; ++r)
                sv[st][r] = (st < nst) ? sacc[st][r] : -INFINITY;
        if (dmask) {
#pragma unroll
            for (int st = 0; st < 4; ++st)
#pragma unroll
                for (int r = 0; r < 4; ++r)
                    if (kv0 + st * 16 + c > q0 + 4 * g + r) sv[st][r] = -INFINITY;
        }

        float rm[4], mnew[4], alpha[4], rs[4];
#pragma unroll
        for (int r = 0; r < 4; ++r)
            rm[r] = fmaxf(fmaxf(sv[0][r], sv[1][r]), fmaxf(sv[2][r], sv[3][r]));
#pragma unroll
        for (int off = 1; off <= 8; off <<= 1)
#pragma unroll
            for (int r = 0; r < 4; ++r)
                rm[r] = fmaxf(rm[r], __shfl_xor(rm[r], off));
#pragma unroll
        for (int r = 0; r < 4; ++r) {
            mnew[r]  = fmaxf(m_r[r], rm[r]);
            alpha[r] = __expf(m_r[r] - mnew[r]);
            rs[r]    = 0.f;
        }

        const int buf = tcnt & 1;
#pragma unroll
        for (int st = 0; st < 4; ++st)
#pragma unroll
            for (int r = 0; r < 4; ++r) {
                float p = __expf(sv[st][r] - mnew[r]);
                rs[r] += p;
                int row = 4 * g + r;
                int off = row * 128 + (st * 16 + c) * 2;
                off ^= (row & 7) << 4;
                *(unsigned short*)((char*)plds[wid][buf] + off) = f2bf(p);
            }
#pragma unroll
        for (int off = 1; off <= 8; off <<= 1)
#pragma unroll
            for (int r = 0; r < 4; ++r)
                rs[r] += __shfl_xor(rs[r], off);
#pragma unroll
        for (int r = 0; r < 4; ++r) {
            l_r[r] = l_r[r] * alpha[r] + rs[r];
            m_r[r] = mnew[r];
        }
#pragma unroll
        for (int ht = 0; ht < 8; ++ht) {
            oacc[ht][0] *= alpha[0]; oacc[ht][1] *= alpha[1];
            oacc[ht][2] *= alpha[2]; oacc[ht][3] *= alpha[3];
        }

        asm volatile("s_waitcnt lgkmcnt(0)" ::: "memory");

        const int nks2 = (nst + 1) >> 1;
        bf16x8 pa[2];
        for (int ks2 = 0; ks2 < nks2; ++ks2) {
            int off = c * 128 + ks2 * 64 + g * 16;
            off ^= (c & 7) << 4;
            pa[ks2] = *(const bf16x8*)((char*)plds[wid][buf] + off);
        }
#pragma unroll
        for (int ht = 0; ht < 8; ++ht) {
            const short* Vrow = Vtb + (size_t)(ht * 16 + c) * TLEN + kv0 + g * 8;
            for (int ks2 = 0; ks2 < nks2; ++ks2) {
                bf16x8 vf = *(const bf16x8*)(Vrow + ks2 * 32);
                oacc[ht] = __builtin_amdgcn_mfma_f32_16x16x32_bf16(pa[ks2], vf, oacc[ht], 0, 0, 0);
            }
        }
        ++tcnt;
    };

    if (!isdiag) {
#pragma unroll
        for (int t = 0; t < 4; ++t)
            tile(kv_base + 64 * t, 4, false);
    } else {
        const int ldt = qc & 3;     // local index of the diagonal tile
        for (int t = 0; t < ldt; ++t)
            tile(kv_base + 64 * t, 4, false);
        tile(kv_base + 64 * ldt, wid + 1, true);
    }

    // ---- store partials (unnormalized) ----
    float* Op = Opart + (size_t)pidx * 64 * 128;
#pragma unroll
    for (int ht = 0; ht < 8; ++ht)
#pragma unroll
        for (int r = 0; r < 4; ++r)
            Op[(size_t)(wid * 16 + 4 * g + r) * 128 + ht * 16 + c] = oacc[ht][r];
    if (c == 0) {
#pragma unroll
        for (int r = 0; r < 4; ++r) {
            mpart[(size_t)pidx * 64 + wid * 16 + 4 * g + r] = m_r[r];
            lpart[(size_t)pidx * 64 + wid * 16 + 4 * g + r] = l_r[r];
        }
    }
}

// ---------------------------------------------------------------------------
// Kernel 2b: combine partials.  Block = one (b, qc); thread t: row = t>>2,
// dims [(t&3)*32, +32).
// ---------------------------------------------------------------------------
__global__ __launch_bounds__(256) void attn_combine(
    const float* __restrict__ Opart, const float* __restrict__ mpart,
    const float* __restrict__ lpart, float* __restrict__ out)
{
    const int qc = blockIdx.x;
    const int b  = blockIdx.y;
    const int gq = qc >> 2;
    const int n  = gq + 1;
    const int base = b * 144 + (gq + 1) * (qc - 2 * gq);
    const int t   = threadIdx.x;
    const int row = t >> 2;
    const int d0  = (t & 3) * 32;

    float M = -INFINITY;
    for (int p = 0; p < n; ++p)
        M = fmaxf(M, mpart[(size_t)(base + p) * 64 + row]);
    float L = 0.f;
    for (int p = 0; p < n; ++p)
        L += __expf(mpart[(size_t)(base + p) * 64 + row] - M) *
             lpart[(size_t)(base + p) * 64 + row];

    float4 acc[8];
#pragma unroll
    for (int i = 0; i < 8; ++i) acc[i] = make_float4(0.f, 0.f, 0.f, 0.f);

    for (int p = 0; p < n; ++p) {
        const float w = __expf(mpart[(size_t)(base + p) * 64 + row] - M);
        const float4* src = (const float4*)(Opart +
            ((size_t)(base + p) * 64 + row) * 128 + d0);
#pragma unroll
        for (int i = 0; i < 8; ++i) {
            float4 v = src[i];
            acc[i].x += w * v.x; acc[i].y += w * v.y;
            acc[i].z += w * v.z; acc[i].w += w * v.w;
        }
    }

    const float invL = 1.f / L;
    float4* dst = (float4*)(out + ((size_t)(b * TLEN + qc * 64 + row)) * 128 + d0);
#pragma unroll
    for (int i = 0; i < 8; ++i) {
        dst[i] = make_float4(acc[i].x * invL, acc[i].y * invL,
                             acc[i].z * invL, acc[i].w * invL);
    }
}

extern "C" void kernel_launch(void* const* d_in, const int* in_sizes, int n_in,
                              void* d_out, int out_size, void* d_ws, size_t ws_size,
                              hipStream_t stream)
{
    const float* x  = (const float*)d_in[0];
    const float* Wq = (const float*)d_in[1];
    const float* Wk = (const float*)d_in[2];
    const float* Wv = (const float*)d_in[3];
    float* outp = (float*)d_out;

    const size_t per = (size_t)BATCH * TLEN * HDIM;      // 4,194,304
    unsigned short* qb  = (unsigned short*)d_ws;
    unsigned short* kb  = qb + per;
    unsigned short* vtb = kb + per;
    unsigned short* wtb = vtb + per;                     // 384*1024
    float* Opart = (float*)(wtb + 384 * 1024);           // 2304*64*128 f32
    float* mpart = Opart + (size_t)2304 * 64 * 128;      // 2304*64
    float* lpart = mpart + (size_t)2304 * 64;            // 2304*64

    dim3 gw(512, 3);
    pack_w<<<gw, 256, 0, stream>>>(Wq, Wk, Wv, wtb);

    dim3 g1((BATCH * TLEN) / 128, 3);
    qkv_mfma<<<g1, 256, 0, stream>>>(x, wtb, qb, kb, vtb);

    dim3 g2(8, 32, BATCH);
    attn_partial<<<g2, 256, 0, stream>>>((const short*)qb, (const short*)kb,
                                         (const short*)vtb, Opart, mpart, lpart);

    dim3 g3(32, BATCH);
    attn_combine<<<g3, 256, 0, stream>>>(Opart, mpart, lpart, outp);
}

// Round 5
// 194.136 us; speedup vs baseline: 23.6287x; 1.7957x over previous
//
#include <hip/hip_runtime.h>
#include <hip/hip_bf16.h>

#define BATCH 16
#define TLEN 2048
#define CDIM 1024
#define HDIM 128

typedef __attribute__((ext_vector_type(8))) short bf16x8;
typedef __attribute__((ext_vector_type(4))) float f32x4;
typedef __attribute__((ext_vector_type(4))) unsigned short u16x4;

static __device__ __forceinline__ unsigned short f2bf(float f) {
    __hip_bfloat16 h = __float2bfloat16(f);
    return *(unsigned short*)&h;
}

// ---------------------------------------------------------------------------
// Prep: pack Wq|Wk|Wv into transposed bf16  wtb[(which*128+n)*1024 + k].
// ---------------------------------------------------------------------------
__global__ __launch_bounds__(256) void pack_w(
    const float* __restrict__ Wq, const float* __restrict__ Wk,
    const float* __restrict__ Wv, unsigned short* __restrict__ wtb)
{
    const int which = blockIdx.y;
    const float* W = (which == 0) ? Wq : (which == 1) ? Wk : Wv;
    const int n = blockIdx.x >> 2;
    const int k = (blockIdx.x & 3) * 256 + threadIdx.x;
    wtb[((size_t)which * 128 + n) * 1024 + k] = f2bf(W[(size_t)k * 128 + n]);
}

// ---------------------------------------------------------------------------
// Kernel 1: QKV projection, bf16 MFMA (unchanged, ~35us).
// ---------------------------------------------------------------------------
__global__ __launch_bounds__(256) void qkv_mfma(
    const float* __restrict__ x, const unsigned short* __restrict__ wtb,
    unsigned short* __restrict__ qb, unsigned short* __restrict__ kb,
    unsigned short* __restrict__ vtb)
{
    __shared__ unsigned short As[128 * 64];
    __shared__ unsigned short Bs[128 * 64];

    const int tid  = threadIdx.x;
    const int lane = tid & 63, wid = tid >> 6;
    const int wm = wid >> 1, wn = wid & 1;
    const int c = lane & 15, g = lane >> 4;
    const int m0 = blockIdx.x * 128;
    const int nt = blockIdx.y;
    const unsigned short* Wp = wtb + (size_t)nt * 128 * 1024;

    f32x4 acc[4][4];
#pragma unroll
    for (int i = 0; i < 4; ++i)
#pragma unroll
        for (int j = 0; j < 4; ++j) acc[i][j] = (f32x4){0.f, 0.f, 0.f, 0.f};

    bf16x8 av[4], bv[4];

#pragma unroll
    for (int i = 0; i < 4; ++i) {
        const int j = tid + i * 256, row = j >> 3, ch = j & 7;
        const float* src = x + (size_t)(m0 + row) * CDIM + ch * 8;
        float4 f0 = *(const float4*)src, f1 = *(const float4*)(src + 4);
        bf16x8 t;
        t[0]=f2bf(f0.x); t[1]=f2bf(f0.y); t[2]=f2bf(f0.z); t[3]=f2bf(f0.w);
        t[4]=f2bf(f1.x); t[5]=f2bf(f1.y); t[6]=f2bf(f1.z); t[7]=f2bf(f1.w);
        av[i] = t;
        bv[i] = *(const bf16x8*)(Wp + (size_t)row * 1024 + ch * 8);
    }
#pragma unroll
    for (int i = 0; i < 4; ++i) {
        const int j = tid + i * 256, row = j >> 3, ch = j & 7;
        const int off = row * 128 + ((ch * 16) ^ ((row & 7) << 4));
        *(bf16x8*)((char*)As + off) = av[i];
        *(bf16x8*)((char*)Bs + off) = bv[i];
    }
    __syncthreads();

#pragma unroll 1
    for (int kt = 0; kt < 16; ++kt) {
        if (kt < 15) {
            const int k0 = (kt + 1) * 64;
#pragma unroll
            for (int i = 0; i < 4; ++i) {
                const int j = tid + i * 256, row = j >> 3, ch = j & 7;
                const float* src = x + (size_t)(m0 + row) * CDIM + k0 + ch * 8;
                float4 f0 = *(const float4*)src, f1 = *(const float4*)(src + 4);
                bf16x8 t;
                t[0]=f2bf(f0.x); t[1]=f2bf(f0.y); t[2]=f2bf(f0.z); t[3]=f2bf(f0.w);
                t[4]=f2bf(f1.x); t[5]=f2bf(f1.y); t[6]=f2bf(f1.z); t[7]=f2bf(f1.w);
                av[i] = t;
                bv[i] = *(const bf16x8*)(Wp + (size_t)row * 1024 + k0 + ch * 8);
            }
        }

#pragma unroll
        for (int ks = 0; ks < 2; ++ks) {
            bf16x8 af[4], bf[4];
#pragma unroll
            for (int mf = 0; mf < 4; ++mf) {
                const int row = wm * 64 + mf * 16 + c;
                const int off = row * 128 + ((ks * 64 + g * 16) ^ ((row & 7) << 4));
                af[mf] = *(const bf16x8*)((char*)As + off);
            }
#pragma unroll
            for (int nf = 0; nf < 4; ++nf) {
                const int row = wn * 64 + nf * 16 + c;
                const int off = row * 128 + ((ks * 64 + g * 16) ^ ((row & 7) << 4));
                bf[nf] = *(const bf16x8*)((char*)Bs + off);
            }
#pragma unroll
            for (int mf = 0; mf < 4; ++mf)
#pragma unroll
                for (int nf = 0; nf < 4; ++nf)
                    acc[mf][nf] = __builtin_amdgcn_mfma_f32_16x16x32_bf16(
                        af[mf], bf[nf], acc[mf][nf], 0, 0, 0);
        }

        if (kt < 15) {
            __syncthreads();
#pragma unroll
            for (int i = 0; i < 4; ++i) {
                const int j = tid + i * 256, row = j >> 3, ch = j & 7;
                const int off = row * 128 + ((ch * 16) ^ ((row & 7) << 4));
                *(bf16x8*)((char*)As + off) = av[i];
                *(bf16x8*)((char*)Bs + off) = bv[i];
            }
            __syncthreads();
        }
    }

    const int mb = m0 + wm * 64, nb = wn * 64;
    if (nt == 0) {
#pragma unroll
        for (int mf = 0; mf < 4; ++mf)
#pragma unroll
            for (int nf = 0; nf < 4; ++nf)
#pragma unroll
                for (int r = 0; r < 4; ++r) {
                    const int m = mb + mf * 16 + g * 4 + r;
                    const int n = nb + nf * 16 + c;
                    qb[(size_t)m * HDIM + n] = f2bf(acc[mf][nf][r] * 0.03125f);
                }
    } else if (nt == 1) {
#pragma unroll
        for (int mf = 0; mf < 4; ++mf)
#pragma unroll
            for (int nf = 0; nf < 4; ++nf)
#pragma unroll
                for (int r = 0; r < 4; ++r) {
                    const int m = mb + mf * 16 + g * 4 + r;
                    const int n = nb + nf * 16 + c;
                    kb[(size_t)m * HDIM + n] = f2bf(acc[mf][nf][r]);
                }
    } else {
#pragma unroll
        for (int mf = 0; mf < 4; ++mf)
#pragma unroll
            for (int nf = 0; nf < 4; ++nf) {
                const int m = mb + mf * 16 + g * 4;
                const int b = m >> 11, t = m & (TLEN - 1);
                const int n = nb + nf * 16 + c;
                u16x4 o;
                o[0] = f2bf(acc[mf][nf][0]); o[1] = f2bf(acc[mf][nf][1]);
                o[2] = f2bf(acc[mf][nf][2]); o[3] = f2bf(acc[mf][nf][3]);
                *(u16x4*)(vtb + ((size_t)b * HDIM + n) * TLEN + t) = o;
            }
    }
}

// ---------------------------------------------------------------------------
// Kernel 2a: flash-attention partials. Task = (b, qc [64 q rows], kc [256 keys]).
// 4 waves/block share K/V tiles via swizzled LDS; reg-staged with async split:
//   prologue: GLOAD(t0)+SSTORE; loop: GLOAD(t+1) | compute(t) | bar | SSTORE | bar
// Wave w owns q rows [64*qc+16*w, +16). Diag chunk: subtile st valid iff st<=w.
// ---------------------------------------------------------------------------
__global__ __launch_bounds__(256) void attn_partial(
    const short* __restrict__ qb, const short* __restrict__ kb,
    const short* __restrict__ vtb,
    float* __restrict__ Opart, float* __restrict__ mpart,
    float* __restrict__ lpart)
{
    const int kc = blockIdx.x;
    const int qc = blockIdx.y;
    const int b  = blockIdx.z;
    const int gq = qc >> 2;
    if (kc > gq) return;
    const bool isdiag = (kc == gq);
    const int NT = isdiag ? (qc & 3) + 1 : 4;

    __shared__ unsigned short Ks[64 * 128];     // 16KB  [key][h], swizzled
    __shared__ unsigned short Vs[128 * 64];     // 16KB  [h][key], swizzled
    __shared__ unsigned short plds[4][16 * 64]; // 8KB   per-wave P

    const int tid  = threadIdx.x;
    const int wid  = tid >> 6;
    const int lane = tid & 63;
    const int g = lane >> 4, c = lane & 15;
    const int q0 = qc * 64 + wid * 16;
    const int kv_base = kc * 256;
    const int pidx = b * 144 + (gq + 1) * (qc - 2 * gq) + kc;

    const short* Kb  = kb  + (size_t)b * TLEN * HDIM;
    const short* Vtb = vtb + (size_t)b * HDIM * TLEN;

    bf16x8 qf[4];
#pragma unroll
    for (int ks = 0; ks < 4; ++ks)
        qf[ks] = *(const bf16x8*)(qb + ((size_t)b * TLEN + q0 + c) * HDIM + ks * 32 + g * 8);

    // staging registers (16B x 4 each for K and V)
    bf16x8 kst[4], vst[4];

    // GLOAD: issue global loads for tile at kv0 (coalesced, unswizzled source)
    // SSTORE: write them into LDS with XOR swizzle (write side == read side)
#define GLOAD(kv0_)                                                          \
    {                                                                        \
        _Pragma("unroll")                                                    \
        for (int it = 0; it < 4; ++it) {                                     \
            const int o = tid * 16 + it * 4096;                              \
            const int kr = o >> 8, kcb = o & 0xF0;                           \
            kst[it] = *(const bf16x8*)((const char*)Kb +                     \
                        (size_t)((kv0_) + kr) * 256 + kcb);                  \
            const int vr = o >> 7, vcb = o & 0x70;                           \
            vst[it] = *(const bf16x8*)((const char*)Vtb +                    \
                        (size_t)vr * (TLEN * 2) + (size_t)(kv0_) * 2 + vcb); \
        }                                                                    \
    }
#define SSTORE()                                                             \
    {                                                                        \
        _Pragma("unroll")                                                    \
        for (int it = 0; it < 4; ++it) {                                     \
            const int o = tid * 16 + it * 4096;                              \
            const int kr = o >> 8, kcb = o & 0xF0;                           \
            *(bf16x8*)((char*)Ks + kr * 256 + (kcb ^ ((kr & 7) << 4))) = kst[it]; \
            const int vr = o >> 7, vcb = o & 0x70;                           \
            *(bf16x8*)((char*)Vs + vr * 128 + (vcb ^ ((vr & 7) << 4))) = vst[it]; \
        }                                                                    \
    }

    GLOAD(kv_base);
    SSTORE();
    __syncthreads();

    f32x4 oacc[8];
#pragma unroll
    for (int i = 0; i < 8; ++i) oacc[i] = (f32x4){0.f, 0.f, 0.f, 0.f};
    float m_r[4] = {-INFINITY, -INFINITY, -INFINITY, -INFINITY};
    float l_r[4] = {0.f, 0.f, 0.f, 0.f};

#pragma unroll 1
    for (int t = 0; t < NT; ++t) {
        // async split: issue next tile's global loads before compute
        if (t + 1 < NT) GLOAD(kv_base + 64 * (t + 1));

        const int kv0 = kv_base + 64 * t;
        const bool dtile = isdiag && (t == NT - 1);
        const int nst = dtile ? (wid + 1) : 4;    // wave-uniform

        // ---- QK^T from LDS ----
        f32x4 sacc[4];
#pragma unroll
        for (int st = 0; st < 4; ++st) sacc[st] = (f32x4){0.f, 0.f, 0.f, 0.f};
#pragma unroll
        for (int st = 0; st < 4; ++st) {
            if (st < nst) {
                const int row = st * 16 + c;
#pragma unroll
                for (int ks = 0; ks < 4; ++ks) {
                    const int off = row * 256 + ((ks * 64 + g * 16) ^ ((row & 7) << 4));
                    bf16x8 kf = *(const bf16x8*)((char*)Ks + off);
                    sacc[st] = __builtin_amdgcn_mfma_f32_16x16x32_bf16(qf[ks], kf, sacc[st], 0, 0, 0);
                }
            }
        }

        // ---- online softmax ----
        float sv[4][4];
#pragma unroll
        for (int st = 0; st < 4; ++st)
#pragma unroll
            for (int r = 0; r < 4; ++r)
                sv[st][r] = (st < nst) ? sacc[st][r] : -INFINITY;
        if (dtile) {
#pragma unroll
            for (int st = 0; st < 4; ++st)
#pragma unroll
                for (int r = 0; r < 4; ++r)
                    if (kv0 + st * 16 + c > q0 + 4 * g + r) sv[st][r] = -INFINITY;
        }

        float rm[4], mnew[4], alpha[4], rs[4];
#pragma unroll
        for (int r = 0; r < 4; ++r)
            rm[r] = fmaxf(fmaxf(sv[0][r], sv[1][r]), fmaxf(sv[2][r], sv[3][r]));
#pragma unroll
        for (int off = 1; off <= 8; off <<= 1)
#pragma unroll
            for (int r = 0; r < 4; ++r)
                rm[r] = fmaxf(rm[r], __shfl_xor(rm[r], off));
#pragma unroll
        for (int r = 0; r < 4; ++r) {
            mnew[r]  = fmaxf(m_r[r], rm[r]);
            alpha[r] = __expf(m_r[r] - mnew[r]);
            rs[r]    = 0.f;
        }

#pragma unroll
        for (int st = 0; st < 4; ++st)
#pragma unroll
            for (int r = 0; r < 4; ++r) {
                float p = __expf(sv[st][r] - mnew[r]);
                rs[r] += p;
                int row = 4 * g + r;
                int off = row * 128 + (st * 16 + c) * 2;
                off ^= (row & 7) << 4;
                *(unsigned short*)((char*)plds[wid] + off) = f2bf(p);
            }
#pragma unroll
        for (int off = 1; off <= 8; off <<= 1)
#pragma unroll
            for (int r = 0; r < 4; ++r)
                rs[r] += __shfl_xor(rs[r], off);
#pragma unroll
        for (int r = 0; r < 4; ++r) {
            l_r[r] = l_r[r] * alpha[r] + rs[r];
            m_r[r] = mnew[r];
        }
#pragma unroll
        for (int ht = 0; ht < 8; ++ht) {
            oacc[ht][0] *= alpha[0]; oacc[ht][1] *= alpha[1];
            oacc[ht][2] *= alpha[2]; oacc[ht][3] *= alpha[3];
        }

        asm volatile("s_waitcnt lgkmcnt(0)" ::: "memory");
        __builtin_amdgcn_sched_barrier(0);

        // ---- PV from LDS ----
        const int nks2 = (nst + 1) >> 1;
        bf16x8 pa[2];
#pragma unroll
        for (int ks2 = 0; ks2 < 2; ++ks2) {
            if (ks2 < nks2) {
                int off = c * 128 + ks2 * 64 + g * 16;
                off ^= (c & 7) << 4;
                pa[ks2] = *(const bf16x8*)((char*)plds[wid] + off);
            }
        }
#pragma unroll
        for (int ht = 0; ht < 8; ++ht) {
            const int row = ht * 16 + c;
#pragma unroll
            for (int ks2 = 0; ks2 < 2; ++ks2) {
                if (ks2 < nks2) {
                    const int off = row * 128 + ((ks2 * 64 + g * 16) ^ ((row & 7) << 4));
                    bf16x8 vf = *(const bf16x8*)((char*)Vs + off);
                    oacc[ht] = __builtin_amdgcn_mfma_f32_16x16x32_bf16(pa[ks2], vf, oacc[ht], 0, 0, 0);
                }
            }
        }

        __syncthreads();              // all waves done reading Ks/Vs
        if (t + 1 < NT) {
            SSTORE();                 // overwrite with prefetched tile
            __syncthreads();
        }
    }

    // ---- store partials (unnormalized) ----
    float* Op = Opart + (size_t)pidx * 64 * 128;
#pragma unroll
    for (int ht = 0; ht < 8; ++ht)
#pragma unroll
        for (int r = 0; r < 4; ++r)
            Op[(size_t)(wid * 16 + 4 * g + r) * 128 + ht * 16 + c] = oacc[ht][r];
    if (c == 0) {
#pragma unroll
        for (int r = 0; r < 4; ++r) {
            mpart[(size_t)pidx * 64 + wid * 16 + 4 * g + r] = m_r[r];
            lpart[(size_t)pidx * 64 + wid * 16 + 4 * g + r] = l_r[r];
        }
    }
#undef GLOAD
#undef SSTORE
}

// ---------------------------------------------------------------------------
// Kernel 2b: combine partials.
// ---------------------------------------------------------------------------
__global__ __launch_bounds__(256) void attn_combine(
    const float* __restrict__ Opart, const float* __restrict__ mpart,
    const float* __restrict__ lpart, float* __restrict__ out)
{
    const int qc = blockIdx.x;
    const int b  = blockIdx.y;
    const int gq = qc >> 2;
    const int n  = gq + 1;
    const int base = b * 144 + (gq + 1) * (qc - 2 * gq);
    const int t   = threadIdx.x;
    const int row = t >> 2;
    const int d0  = (t & 3) * 32;

    float M = -INFINITY;
    for (int p = 0; p < n; ++p)
        M = fmaxf(M, mpart[(size_t)(base + p) * 64 + row]);
    float L = 0.f;
    for (int p = 0; p < n; ++p)
        L += __expf(mpart[(size_t)(base + p) * 64 + row] - M) *
             lpart[(size_t)(base + p) * 64 + row];

    float4 acc[8];
#pragma unroll
    for (int i = 0; i < 8; ++i) acc[i] = make_float4(0.f, 0.f, 0.f, 0.f);

    for (int p = 0; p < n; ++p) {
        const float w = __expf(mpart[(size_t)(base + p) * 64 + row] - M);
        const float4* src = (const float4*)(Opart +
            ((size_t)(base + p) * 64 + row) * 128 + d0);
#pragma unroll
        for (int i = 0; i < 8; ++i) {
            float4 v = src[i];
            acc[i].x += w * v.x; acc[i].y += w * v.y;
            acc[i].z += w * v.z; acc[i].w += w * v.w;
        }
    }

    const float invL = 1.f / L;
    float4* dst = (float4*)(out + ((size_t)(b * TLEN + qc * 64 + row)) * 128 + d0);
#pragma unroll
    for (int i = 0; i < 8; ++i) {
        dst[i] = make_float4(acc[i].x * invL, acc[i].y * invL,
                             acc[i].z * invL, acc[i].w * invL);
    }
}

extern "C" void kernel_launch(void* const* d_in, const int* in_sizes, int n_in,
                              void* d_out, int out_size, void* d_ws, size_t ws_size,
                              hipStream_t stream)
{
    const float* x  = (const float*)d_in[0];
    const float* Wq = (const float*)d_in[1];
    const float* Wk = (const float*)d_in[2];
    const float* Wv = (const float*)d_in[3];
    float* outp = (float*)d_out;

    const size_t per = (size_t)BATCH * TLEN * HDIM;      // 4,194,304
    unsigned short* qb  = (unsigned short*)d_ws;
    unsigned short* kb  = qb + per;
    unsigned short* vtb = kb + per;
    unsigned short* wtb = vtb + per;                     // 384*1024
    float* Opart = (float*)(wtb + 384 * 1024);           // 2304*64*128 f32
    float* mpart = Opart + (size_t)2304 * 64 * 128;      // 2304*64
    float* lpart = mpart + (size_t)2304 * 64;            // 2304*64

    dim3 gw(512, 3);
    pack_w<<<gw, 256, 0, stream>>>(Wq, Wk, Wv, wtb);

    dim3 g1((BATCH * TLEN) / 128, 3);
    qkv_mfma<<<g1, 256, 0, stream>>>(x, wtb, qb, kb, vtb);

    dim3 g2(8, 32, BATCH);
    attn_partial<<<g2, 256, 0, stream>>>((const short*)qb, (const short*)kb,
                                         (const short*)vtb, Opart, mpart, lpart);

    dim3 g3(32, BATCH);
    attn_combine<<<g3, 256, 0, stream>>>(Opart, mpart, lpart, outp);
}

// Round 6
// 178.970 us; speedup vs baseline: 25.6311x; 1.0847x over previous
//
#include <hip/hip_runtime.h>
#include <hip/hip_bf16.h>

#define BATCH 16
#define TLEN 2048
#define CDIM 1024
#define HDIM 128

typedef __attribute__((ext_vector_type(8))) short bf16x8;
typedef __attribute__((ext_vector_type(4))) float f32x4;
typedef __attribute__((ext_vector_type(4))) unsigned short u16x4;

static __device__ __forceinline__ unsigned short f2bf(float f) {
    __hip_bfloat16 h = __float2bfloat16(f);
    return *(unsigned short*)&h;
}
static __device__ __forceinline__ float bf2f(unsigned short u) {
    union { unsigned u; float f; } x; x.u = (unsigned)u << 16; return x.f;
}
// partials per (b,qc) prefix:  sum_{j<qc} (j/2 + 1)
static __device__ __forceinline__ int part_offs(int qc) {
    return qc + ((qc * qc - 2 * qc + (qc & 1)) >> 2);
}

// ---------------------------------------------------------------------------
// Prep: pack Wq|Wk|Wv into transposed bf16  wtb[(which*128+n)*1024 + k].
// ---------------------------------------------------------------------------
__global__ __launch_bounds__(256) void pack_w(
    const float* __restrict__ Wq, const float* __restrict__ Wk,
    const float* __restrict__ Wv, unsigned short* __restrict__ wtb)
{
    const int which = blockIdx.y;
    const float* W = (which == 0) ? Wq : (which == 1) ? Wk : Wv;
    const int n = blockIdx.x >> 2;
    const int k = (blockIdx.x & 3) * 256 + threadIdx.x;
    wtb[((size_t)which * 128 + n) * 1024 + k] = f2bf(W[(size_t)k * 128 + n]);
}

// ---------------------------------------------------------------------------
// Kernel 1: QKV projection, bf16 MFMA.  1D grid, XCD-aware swizzle so the 3
// blocks sharing one x-tile run back-to-back on the SAME XCD (x read once).
// ---------------------------------------------------------------------------
__global__ __launch_bounds__(256) void qkv_mfma(
    const float* __restrict__ x, const unsigned short* __restrict__ wtb,
    unsigned short* __restrict__ qb, unsigned short* __restrict__ kb,
    unsigned short* __restrict__ vtb)
{
    __shared__ unsigned short As[128 * 64];
    __shared__ unsigned short Bs[128 * 64];

    const int bid = blockIdx.x;           // 0..767
    const int xcd = bid & 7, s = bid >> 3; // s in 0..95
    const int m0 = (xcd * 32 + s / 3) * 128;
    const int nt = s % 3;

    const int tid  = threadIdx.x;
    const int lane = tid & 63, wid = tid >> 6;
    const int wm = wid >> 1, wn = wid & 1;
    const int c = lane & 15, g = lane >> 4;
    const unsigned short* Wp = wtb + (size_t)nt * 128 * 1024;

    f32x4 acc[4][4];
#pragma unroll
    for (int i = 0; i < 4; ++i)
#pragma unroll
        for (int j = 0; j < 4; ++j) acc[i][j] = (f32x4){0.f, 0.f, 0.f, 0.f};

    bf16x8 av[4], bv[4];

#pragma unroll
    for (int i = 0; i < 4; ++i) {
        const int j = tid + i * 256, row = j >> 3, ch = j & 7;
        const float* src = x + (size_t)(m0 + row) * CDIM + ch * 8;
        float4 f0 = *(const float4*)src, f1 = *(const float4*)(src + 4);
        bf16x8 t;
        t[0]=f2bf(f0.x); t[1]=f2bf(f0.y); t[2]=f2bf(f0.z); t[3]=f2bf(f0.w);
        t[4]=f2bf(f1.x); t[5]=f2bf(f1.y); t[6]=f2bf(f1.z); t[7]=f2bf(f1.w);
        av[i] = t;
        bv[i] = *(const bf16x8*)(Wp + (size_t)row * 1024 + ch * 8);
    }
#pragma unroll
    for (int i = 0; i < 4; ++i) {
        const int j = tid + i * 256, row = j >> 3, ch = j & 7;
        const int off = row * 128 + ((ch * 16) ^ ((row & 7) << 4));
        *(bf16x8*)((char*)As + off) = av[i];
        *(bf16x8*)((char*)Bs + off) = bv[i];
    }
    __syncthreads();

#pragma unroll 1
    for (int kt = 0; kt < 16; ++kt) {
        if (kt < 15) {
            const int k0 = (kt + 1) * 64;
#pragma unroll
            for (int i = 0; i < 4; ++i) {
                const int j = tid + i * 256, row = j >> 3, ch = j & 7;
                const float* src = x + (size_t)(m0 + row) * CDIM + k0 + ch * 8;
                float4 f0 = *(const float4*)src, f1 = *(const float4*)(src + 4);
                bf16x8 t;
                t[0]=f2bf(f0.x); t[1]=f2bf(f0.y); t[2]=f2bf(f0.z); t[3]=f2bf(f0.w);
                t[4]=f2bf(f1.x); t[5]=f2bf(f1.y); t[6]=f2bf(f1.z); t[7]=f2bf(f1.w);
                av[i] = t;
                bv[i] = *(const bf16x8*)(Wp + (size_t)row * 1024 + k0 + ch * 8);
            }
        }

#pragma unroll
        for (int ks = 0; ks < 2; ++ks) {
            bf16x8 af[4], bf[4];
#pragma unroll
            for (int mf = 0; mf < 4; ++mf) {
                const int row = wm * 64 + mf * 16 + c;
                const int off = row * 128 + ((ks * 64 + g * 16) ^ ((row & 7) << 4));
                af[mf] = *(const bf16x8*)((char*)As + off);
            }
#pragma unroll
            for (int nf = 0; nf < 4; ++nf) {
                const int row = wn * 64 + nf * 16 + c;
                const int off = row * 128 + ((ks * 64 + g * 16) ^ ((row & 7) << 4));
                bf[nf] = *(const bf16x8*)((char*)Bs + off);
            }
#pragma unroll
            for (int mf = 0; mf < 4; ++mf)
#pragma unroll
                for (int nf = 0; nf < 4; ++nf)
                    acc[mf][nf] = __builtin_amdgcn_mfma_f32_16x16x32_bf16(
                        af[mf], bf[nf], acc[mf][nf], 0, 0, 0);
        }

        if (kt < 15) {
            __syncthreads();
#pragma unroll
            for (int i = 0; i < 4; ++i) {
                const int j = tid + i * 256, row = j >> 3, ch = j & 7;
                const int off = row * 128 + ((ch * 16) ^ ((row & 7) << 4));
                *(bf16x8*)((char*)As + off) = av[i];
                *(bf16x8*)((char*)Bs + off) = bv[i];
            }
            __syncthreads();
        }
    }

    const int mb = m0 + wm * 64, nb = wn * 64;
    if (nt == 0) {
#pragma unroll
        for (int mf = 0; mf < 4; ++mf)
#pragma unroll
            for (int nf = 0; nf < 4; ++nf)
#pragma unroll
                for (int r = 0; r < 4; ++r) {
                    const int m = mb + mf * 16 + g * 4 + r;
                    const int n = nb + nf * 16 + c;
                    qb[(size_t)m * HDIM + n] = f2bf(acc[mf][nf][r] * 0.03125f);
                }
    } else if (nt == 1) {
#pragma unroll
        for (int mf = 0; mf < 4; ++mf)
#pragma unroll
            for (int nf = 0; nf < 4; ++nf)
#pragma unroll
                for (int r = 0; r < 4; ++r) {
                    const int m = mb + mf * 16 + g * 4 + r;
                    const int n = nb + nf * 16 + c;
                    kb[(size_t)m * HDIM + n] = f2bf(acc[mf][nf][r]);
                }
    } else {
#pragma unroll
        for (int mf = 0; mf < 4; ++mf)
#pragma unroll
            for (int nf = 0; nf < 4; ++nf) {
                const int m = mb + mf * 16 + g * 4;
                const int b = m >> 11, t = m & (TLEN - 1);
                const int n = nb + nf * 16 + c;
                u16x4 o;
                o[0] = f2bf(acc[mf][nf][0]); o[1] = f2bf(acc[mf][nf][1]);
                o[2] = f2bf(acc[mf][nf][2]); o[3] = f2bf(acc[mf][nf][3]);
                *(u16x4*)(vtb + ((size_t)b * HDIM + n) * TLEN + t) = o;
            }
    }
}

// ---------------------------------------------------------------------------
// Kernel 2a: flash-attention partials.
// Task = (b, qc [128 q rows], kc [256 keys]), active iff kc <= qc/2.
// 8 waves/block, wave w owns rows [qc*128+16w, +16). K/V double-buffered in
// swizzled LDS (one barrier per 64-key tile); async reg-staged prefetch.
// Partials stored bf16 (unnormalized) + per-row m,l (f32).
// ---------------------------------------------------------------------------
__global__ __launch_bounds__(512) void attn_partial(
    const short* __restrict__ qb, const short* __restrict__ kb,
    const short* __restrict__ vtb,
    unsigned short* __restrict__ Opart, float* __restrict__ mpart,
    float* __restrict__ lpart)
{
    const int kc = blockIdx.x;          // 0..7   (256-key chunk)
    const int qc = blockIdx.y;          // 0..15  (128-row chunk)
    const int b  = blockIdx.z;
    if (kc > (qc >> 1)) return;
    const int kv_base = kc * 256;
    const int qrel = qc * 128 - kv_base;             // >= 0 for active blocks
    int NT = ((qrel + 127) >> 6) + 1; if (NT > 4) NT = 4;

    __shared__ unsigned short Ks[2][64 * 128];   // 32KB [buf][key][h] swizzled
    __shared__ unsigned short Vs[2][128 * 64];   // 32KB [buf][h][key] swizzled
    __shared__ unsigned short plds[8][16 * 64];  // 16KB per-wave P

    const int tid  = threadIdx.x;
    const int wid  = tid >> 6;
    const int lane = tid & 63;
    const int g = lane >> 4, c = lane & 15;
    const int q0 = qc * 128 + wid * 16;
    const int pidx = b * 72 + part_offs(qc) + kc;

    const short* Kb  = kb  + (size_t)b * TLEN * HDIM;
    const short* Vtb = vtb + (size_t)b * HDIM * TLEN;

    bf16x8 qf[4];
#pragma unroll
    for (int ks = 0; ks < 4; ++ks)
        qf[ks] = *(const bf16x8*)(qb + ((size_t)b * TLEN + q0 + c) * HDIM + ks * 32 + g * 8);

    bf16x8 kst[2], vst[2];

#define GLOAD(kv0_)                                                          \
    {                                                                        \
        _Pragma("unroll")                                                    \
        for (int it = 0; it < 2; ++it) {                                     \
            const int o = tid * 16 + it * 8192;                              \
            const int kr = o >> 8, kcb = o & 0xF0;                           \
            kst[it] = *(const bf16x8*)((const char*)Kb +                     \
                        (size_t)((kv0_) + kr) * 256 + kcb);                  \
            const int vr = o >> 7, vcb = o & 0x70;                           \
            vst[it] = *(const bf16x8*)((const char*)Vtb +                    \
                        (size_t)vr * (TLEN * 2) + (size_t)(kv0_) * 2 + vcb); \
        }                                                                    \
    }
#define SSTORE(bi_)                                                          \
    {                                                                        \
        _Pragma("unroll")                                                    \
        for (int it = 0; it < 2; ++it) {                                     \
            const int o = tid * 16 + it * 8192;                              \
            const int kr = o >> 8, kcb = o & 0xF0;                           \
            *(bf16x8*)((char*)Ks[bi_] + kr * 256 + (kcb ^ ((kr & 7) << 4))) = kst[it]; \
            const int vr = o >> 7, vcb = o & 0x70;                           \
            *(bf16x8*)((char*)Vs[bi_] + vr * 128 + (vcb ^ ((vr & 7) << 4))) = vst[it]; \
        }                                                                    \
    }

    GLOAD(kv_base);
    SSTORE(0);
    __syncthreads();

    f32x4 oacc[8];
#pragma unroll
    for (int i = 0; i < 8; ++i) oacc[i] = (f32x4){0.f, 0.f, 0.f, 0.f};
    float m_r[4] = {-INFINITY, -INFINITY, -INFINITY, -INFINITY};
    float l_r[4] = {0.f, 0.f, 0.f, 0.f};

#pragma unroll 1
    for (int t = 0; t < NT; ++t) {
        const int bi = t & 1;
        if (t + 1 < NT) GLOAD(kv_base + 64 * (t + 1));

        const int kv0 = kv_base + 64 * t;
        const int dq = q0 + 15 - kv0;
        int nst = (dq < 0) ? 0 : ((dq >> 4) + 1); if (nst > 4) nst = 4;

        if (nst > 0) {
            const bool dmask = (kv0 + nst * 16 - 1) > q0;

            // ---- QK^T from LDS ----
            f32x4 sacc[4];
#pragma unroll
            for (int st = 0; st < 4; ++st) sacc[st] = (f32x4){0.f, 0.f, 0.f, 0.f};
#pragma unroll
            for (int st = 0; st < 4; ++st) {
                if (st < nst) {
                    const int row = st * 16 + c;
#pragma unroll
                    for (int ks = 0; ks < 4; ++ks) {
                        const int off = row * 256 + ((ks * 64 + g * 16) ^ ((row & 7) << 4));
                        bf16x8 kf = *(const bf16x8*)((char*)Ks[bi] + off);
                        sacc[st] = __builtin_amdgcn_mfma_f32_16x16x32_bf16(qf[ks], kf, sacc[st], 0, 0, 0);
                    }
                }
            }

            // ---- online softmax ----
            float sv[4][4];
#pragma unroll
            for (int st = 0; st < 4; ++st)
#pragma unroll
                for (int r = 0; r < 4; ++r)
                    sv[st][r] = (st < nst) ? sacc[st][r] : -INFINITY;
            if (dmask) {
#pragma unroll
                for (int st = 0; st < 4; ++st)
#pragma unroll
                    for (int r = 0; r < 4; ++r)
                        if (kv0 + st * 16 + c > q0 + 4 * g + r) sv[st][r] = -INFINITY;
            }

            float rm[4], mnew[4], alpha[4], rs[4];
#pragma unroll
            for (int r = 0; r < 4; ++r)
                rm[r] = fmaxf(fmaxf(sv[0][r], sv[1][r]), fmaxf(sv[2][r], sv[3][r]));
#pragma unroll
            for (int off = 1; off <= 8; off <<= 1)
#pragma unroll
                for (int r = 0; r < 4; ++r)
                    rm[r] = fmaxf(rm[r], __shfl_xor(rm[r], off));
#pragma unroll
            for (int r = 0; r < 4; ++r) {
                mnew[r]  = fmaxf(m_r[r], rm[r]);
                alpha[r] = __expf(m_r[r] - mnew[r]);
                rs[r]    = 0.f;
            }

#pragma unroll
            for (int st = 0; st < 4; ++st)
#pragma unroll
                for (int r = 0; r < 4; ++r) {
                    float p = __expf(sv[st][r] - mnew[r]);
                    rs[r] += p;
                    int row = 4 * g + r;
                    int off = row * 128 + (st * 16 + c) * 2;
                    off ^= (row & 7) << 4;
                    *(unsigned short*)((char*)plds[wid] + off) = f2bf(p);
                }
#pragma unroll
            for (int off = 1; off <= 8; off <<= 1)
#pragma unroll
                for (int r = 0; r < 4; ++r)
                    rs[r] += __shfl_xor(rs[r], off);
#pragma unroll
            for (int r = 0; r < 4; ++r) {
                l_r[r] = l_r[r] * alpha[r] + rs[r];
                m_r[r] = mnew[r];
            }
#pragma unroll
            for (int ht = 0; ht < 8; ++ht) {
                oacc[ht][0] *= alpha[0]; oacc[ht][1] *= alpha[1];
                oacc[ht][2] *= alpha[2]; oacc[ht][3] *= alpha[3];
            }

            asm volatile("s_waitcnt lgkmcnt(0)" ::: "memory");
            __builtin_amdgcn_sched_barrier(0);

            // ---- PV from LDS ----
            const int nks2 = (nst + 1) >> 1;
            bf16x8 pa[2];
#pragma unroll
            for (int ks2 = 0; ks2 < 2; ++ks2) {
                if (ks2 < nks2) {
                    int off = c * 128 + ks2 * 64 + g * 16;
                    off ^= (c & 7) << 4;
                    pa[ks2] = *(const bf16x8*)((char*)plds[wid] + off);
                }
            }
#pragma unroll
            for (int ht = 0; ht < 8; ++ht) {
                const int row = ht * 16 + c;
#pragma unroll
                for (int ks2 = 0; ks2 < 2; ++ks2) {
                    if (ks2 < nks2) {
                        const int off = row * 128 + ((ks2 * 64 + g * 16) ^ ((row & 7) << 4));
                        bf16x8 vf = *(const bf16x8*)((char*)Vs[bi] + off);
                        oacc[ht] = __builtin_amdgcn_mfma_f32_16x16x32_bf16(pa[ks2], vf, oacc[ht], 0, 0, 0);
                    }
                }
            }
        }

        if (t + 1 < NT) {
            SSTORE(bi ^ 1);          // waits on its own vmcnt deps
            __syncthreads();         // single barrier per tile
        }
    }

    // ---- store partials (unnormalized, bf16) ----
    unsigned short* Op = Opart + (size_t)pidx * 128 * 128;
#pragma unroll
    for (int ht = 0; ht < 8; ++ht)
#pragma unroll
        for (int r = 0; r < 4; ++r)
            Op[(size_t)(wid * 16 + 4 * g + r) * 128 + ht * 16 + c] = f2bf(oacc[ht][r]);
    if (c == 0) {
#pragma unroll
        for (int r = 0; r < 4; ++r) {
            mpart[(size_t)pidx * 128 + wid * 16 + 4 * g + r] = m_r[r];
            lpart[(size_t)pidx * 128 + wid * 16 + 4 * g + r] = l_r[r];
        }
    }
#undef GLOAD
#undef SSTORE
}

// ---------------------------------------------------------------------------
// Kernel 2b: combine partials. Block = (qc, b); thread t: row = t>>1,
// dims [(t&1)*64, +64).
// ---------------------------------------------------------------------------
__global__ __launch_bounds__(256) void attn_combine(
    const unsigned short* __restrict__ Opart, const float* __restrict__ mpart,
    const float* __restrict__ lpart, float* __restrict__ out)
{
    const int qc = blockIdx.x;
    const int b  = blockIdx.y;
    const int n  = (qc >> 1) + 1;
    const int base = b * 72 + part_offs(qc);
    const int t   = threadIdx.x;
    const int row = t >> 1;
    const int d0  = (t & 1) * 64;

    float M = -INFINITY;
    for (int p = 0; p < n; ++p)
        M = fmaxf(M, mpart[(size_t)(base + p) * 128 + row]);
    float L = 0.f;
    for (int p = 0; p < n; ++p)
        L += __expf(mpart[(size_t)(base + p) * 128 + row] - M) *
             lpart[(size_t)(base + p) * 128 + row];

    float acc[64];
#pragma unroll
    for (int i = 0; i < 64; ++i) acc[i] = 0.f;

    for (int p = 0; p < n; ++p) {
        const float w = __expf(mpart[(size_t)(base + p) * 128 + row] - M);
        const bf16x8* src = (const bf16x8*)(Opart +
            ((size_t)(base + p) * 128 + row) * 128 + d0);
#pragma unroll
        for (int j = 0; j < 8; ++j) {
            bf16x8 v = src[j];
#pragma unroll
            for (int e = 0; e < 8; ++e)
                acc[j * 8 + e] += w * bf2f((unsigned short)v[e]);
        }
    }

    const float invL = 1.f / L;
    float4* dst = (float4*)(out + ((size_t)(b * TLEN + qc * 128 + row)) * 128 + d0);
#pragma unroll
    for (int i = 0; i < 16; ++i)
        dst[i] = make_float4(acc[4*i] * invL, acc[4*i+1] * invL,
                             acc[4*i+2] * invL, acc[4*i+3] * invL);
}

extern "C" void kernel_launch(void* const* d_in, const int* in_sizes, int n_in,
                              void* d_out, int out_size, void* d_ws, size_t ws_size,
                              hipStream_t stream)
{
    const float* x  = (const float*)d_in[0];
    const float* Wq = (const float*)d_in[1];
    const float* Wk = (const float*)d_in[2];
    const float* Wv = (const float*)d_in[3];
    float* outp = (float*)d_out;

    const size_t per = (size_t)BATCH * TLEN * HDIM;      // 4,194,304
    unsigned short* qb  = (unsigned short*)d_ws;
    unsigned short* kb  = qb + per;
    unsigned short* vtb = kb + per;
    unsigned short* wtb = vtb + per;                     // 384*1024 bf16
    unsigned short* Opart = wtb + 384 * 1024;            // 1152*128*128 bf16
    float* mpart = (float*)(Opart + (size_t)1152 * 128 * 128);
    float* lpart = mpart + (size_t)1152 * 128;

    dim3 gw(512, 3);
    pack_w<<<gw, 256, 0, stream>>>(Wq, Wk, Wv, wtb);

    qkv_mfma<<<768, 256, 0, stream>>>(x, wtb, qb, kb, vtb);

    dim3 g2(8, 16, BATCH);
    attn_partial<<<g2, 512, 0, stream>>>((const short*)qb, (const short*)kb,
                                         (const short*)vtb, Opart, mpart, lpart);

    dim3 g3(16, BATCH);
    attn_combine<<<g3, 256, 0, stream>>>(Opart, mpart, lpart, outp);
}

// Round 7
// 138.419 us; speedup vs baseline: 33.1400x; 1.2930x over previous
//
#include <hip/hip_runtime.h>
#include <hip/hip_bf16.h>

#define BATCH 16
#define TLEN 2048
#define CDIM 1024
#define HDIM 128

typedef __attribute__((ext_vector_type(8))) short bf16x8;
typedef __attribute__((ext_vector_type(4))) float f32x4;
typedef __attribute__((ext_vector_type(16))) float f32x16;
typedef __attribute__((ext_vector_type(4))) unsigned short u16x4;
typedef __attribute__((ext_vector_type(8))) unsigned short u16x8;

static __device__ __forceinline__ unsigned short f2bf(float f) {
    __hip_bfloat16 h = __float2bfloat16(f);
    return *(unsigned short*)&h;
}
static __device__ __forceinline__ unsigned pkbf(float a, float b) {
    return (unsigned)f2bf(a) | ((unsigned)f2bf(b) << 16);
}
// partials per (b,qc) prefix:  sum_{j<qc} (j/2 + 1)
static __device__ __forceinline__ int part_offs(int qc) {
    return qc + ((qc * qc - 2 * qc + (qc & 1)) >> 2);
}

// ---------------------------------------------------------------------------
// Prep: pack Wq|Wk|Wv into transposed bf16  wtb[(which*128+n)*1024 + k].
// ---------------------------------------------------------------------------
__global__ __launch_bounds__(256) void pack_w(
    const float* __restrict__ Wq, const float* __restrict__ Wk,
    const float* __restrict__ Wv, unsigned short* __restrict__ wtb)
{
    const int which = blockIdx.y;
    const float* W = (which == 0) ? Wq : (which == 1) ? Wk : Wv;
    const int n = blockIdx.x >> 2;
    const int k = (blockIdx.x & 3) * 256 + threadIdx.x;
    wtb[((size_t)which * 128 + n) * 1024 + k] = f2bf(W[(size_t)k * 128 + n]);
}

// ---------------------------------------------------------------------------
// Kernel 1: QKV projection, bf16 MFMA (unchanged from round 6).
// ---------------------------------------------------------------------------
__global__ __launch_bounds__(256) void qkv_mfma(
    const float* __restrict__ x, const unsigned short* __restrict__ wtb,
    unsigned short* __restrict__ qb, unsigned short* __restrict__ kb,
    unsigned short* __restrict__ vtb)
{
    __shared__ unsigned short As[128 * 64];
    __shared__ unsigned short Bs[128 * 64];

    const int bid = blockIdx.x;
    const int xcd = bid & 7, s = bid >> 3;
    const int m0 = (xcd * 32 + s / 3) * 128;
    const int nt = s % 3;

    const int tid  = threadIdx.x;
    const int lane = tid & 63, wid = tid >> 6;
    const int wm = wid >> 1, wn = wid & 1;
    const int c = lane & 15, g = lane >> 4;
    const unsigned short* Wp = wtb + (size_t)nt * 128 * 1024;

    f32x4 acc[4][4];
#pragma unroll
    for (int i = 0; i < 4; ++i)
#pragma unroll
        for (int j = 0; j < 4; ++j) acc[i][j] = (f32x4){0.f, 0.f, 0.f, 0.f};

    bf16x8 av[4], bv[4];

#pragma unroll
    for (int i = 0; i < 4; ++i) {
        const int j = tid + i * 256, row = j >> 3, ch = j & 7;
        const float* src = x + (size_t)(m0 + row) * CDIM + ch * 8;
        float4 f0 = *(const float4*)src, f1 = *(const float4*)(src + 4);
        bf16x8 t;
        t[0]=f2bf(f0.x); t[1]=f2bf(f0.y); t[2]=f2bf(f0.z); t[3]=f2bf(f0.w);
        t[4]=f2bf(f1.x); t[5]=f2bf(f1.y); t[6]=f2bf(f1.z); t[7]=f2bf(f1.w);
        av[i] = t;
        bv[i] = *(const bf16x8*)(Wp + (size_t)row * 1024 + ch * 8);
    }
#pragma unroll
    for (int i = 0; i < 4; ++i) {
        const int j = tid + i * 256, row = j >> 3, ch = j & 7;
        const int off = row * 128 + ((ch * 16) ^ ((row & 7) << 4));
        *(bf16x8*)((char*)As + off) = av[i];
        *(bf16x8*)((char*)Bs + off) = bv[i];
    }
    __syncthreads();

#pragma unroll 1
    for (int kt = 0; kt < 16; ++kt) {
        if (kt < 15) {
            const int k0 = (kt + 1) * 64;
#pragma unroll
            for (int i = 0; i < 4; ++i) {
                const int j = tid + i * 256, row = j >> 3, ch = j & 7;
                const float* src = x + (size_t)(m0 + row) * CDIM + k0 + ch * 8;
                float4 f0 = *(const float4*)src, f1 = *(const float4*)(src + 4);
                bf16x8 t;
                t[0]=f2bf(f0.x); t[1]=f2bf(f0.y); t[2]=f2bf(f0.z); t[3]=f2bf(f0.w);
                t[4]=f2bf(f1.x); t[5]=f2bf(f1.y); t[6]=f2bf(f1.z); t[7]=f2bf(f1.w);
                av[i] = t;
                bv[i] = *(const bf16x8*)(Wp + (size_t)row * 1024 + k0 + ch * 8);
            }
        }

#pragma unroll
        for (int ks = 0; ks < 2; ++ks) {
            bf16x8 af[4], bf[4];
#pragma unroll
            for (int mf = 0; mf < 4; ++mf) {
                const int row = wm * 64 + mf * 16 + c;
                const int off = row * 128 + ((ks * 64 + g * 16) ^ ((row & 7) << 4));
                af[mf] = *(const bf16x8*)((char*)As + off);
            }
#pragma unroll
            for (int nf = 0; nf < 4; ++nf) {
                const int row = wn * 64 + nf * 16 + c;
                const int off = row * 128 + ((ks * 64 + g * 16) ^ ((row & 7) << 4));
                bf[nf] = *(const bf16x8*)((char*)Bs + off);
            }
#pragma unroll
            for (int mf = 0; mf < 4; ++mf)
#pragma unroll
                for (int nf = 0; nf < 4; ++nf)
                    acc[mf][nf] = __builtin_amdgcn_mfma_f32_16x16x32_bf16(
                        af[mf], bf[nf], acc[mf][nf], 0, 0, 0);
        }

        if (kt < 15) {
            __syncthreads();
#pragma unroll
            for (int i = 0; i < 4; ++i) {
                const int j = tid + i * 256, row = j >> 3, ch = j & 7;
                const int off = row * 128 + ((ch * 16) ^ ((row & 7) << 4));
                *(bf16x8*)((char*)As + off) = av[i];
                *(bf16x8*)((char*)Bs + off) = bv[i];
            }
            __syncthreads();
        }
    }

    const int mb = m0 + wm * 64, nb = wn * 64;
    if (nt == 0) {
#pragma unroll
        for (int mf = 0; mf < 4; ++mf)
#pragma unroll
            for (int nf = 0; nf < 4; ++nf)
#pragma unroll
                for (int r = 0; r < 4; ++r) {
                    const int m = mb + mf * 16 + g * 4 + r;
                    const int n = nb + nf * 16 + c;
                    qb[(size_t)m * HDIM + n] = f2bf(acc[mf][nf][r] * 0.03125f);
                }
    } else if (nt == 1) {
#pragma unroll
        for (int mf = 0; mf < 4; ++mf)
#pragma unroll
            for (int nf = 0; nf < 4; ++nf)
#pragma unroll
                for (int r = 0; r < 4; ++r) {
                    const int m = mb + mf * 16 + g * 4 + r;
                    const int n = nb + nf * 16 + c;
                    kb[(size_t)m * HDIM + n] = f2bf(acc[mf][nf][r]);
                }
    } else {
#pragma unroll
        for (int mf = 0; mf < 4; ++mf)
#pragma unroll
            for (int nf = 0; nf < 4; ++nf) {
                const int m = mb + mf * 16 + g * 4;
                const int b = m >> 11, t = m & (TLEN - 1);
                const int n = nb + nf * 16 + c;
                u16x4 o;
                o[0] = f2bf(acc[mf][nf][0]); o[1] = f2bf(acc[mf][nf][1]);
                o[2] = f2bf(acc[mf][nf][2]); o[3] = f2bf(acc[mf][nf][3]);
                *(u16x4*)(vtb + ((size_t)b * HDIM + n) * TLEN + t) = o;
            }
    }
}

// ---------------------------------------------------------------------------
// Kernel 2a: flash-attention partials, 32x32 swapped-operand structure.
// Task = (b, qc [128 q rows], kc [256 keys]), active iff kc <= qc/2.
// 4 waves/block, wave w owns q rows [qc*128+32w, +32); lane q = q0w + (lane&31).
// QK^T = mfma(K, Q)  -> lane holds 32 scores of its own q-row (16 per 32-key
// block, partner lane^32 holds the other 16 of each block).
// PV   = mfma(V^T, P^T) -> O q-column = lane&31, alpha rescale lane-local.
// K/V double-buffered in swizzled LDS; softmax fully in-register; defer-max.
// ---------------------------------------------------------------------------
__global__ __launch_bounds__(256, 2) void attn_partial(
    const short* __restrict__ qb, const short* __restrict__ kb,
    const short* __restrict__ vtb,
    unsigned short* __restrict__ Opart, float* __restrict__ mpart,
    float* __restrict__ lpart)
{
    const int kc = blockIdx.x;          // 0..7   (256-key chunk)
    const int qc = blockIdx.y;          // 0..15  (128-row chunk)
    const int b  = blockIdx.z;
    if (kc > (qc >> 1)) return;
    const int kv_base = kc * 256;
    const int qrel = qc * 128 - kv_base;             // >= 0 for active blocks
    int NT = ((qrel + 127) >> 6) + 1; if (NT > 4) NT = 4;

    __shared__ unsigned short Ks[2][64 * 128];   // 32KB [buf][key][h] swizzled
    __shared__ unsigned short Vs[2][128 * 64];   // 32KB [buf][h][key] swizzled

    const int tid  = threadIdx.x;
    const int wid  = tid >> 6;
    const int lane = tid & 63;
    const int c5 = lane & 31, hi = lane >> 5;
    const int q0w = qc * 128 + wid * 32;
    const int qg  = q0w + c5;                        // this lane's q row
    const int pidx = b * 72 + part_offs(qc) + kc;

    const short* Kb  = kb  + (size_t)b * TLEN * HDIM;
    const short* Vtb = vtb + (size_t)b * HDIM * TLEN;

    // Q fragments (B-operand of swapped QK^T): lane holds Q[qg][hi*8+j + ks*16]
    bf16x8 qf[8];
#pragma unroll
    for (int ks = 0; ks < 8; ++ks)
        qf[ks] = *(const bf16x8*)(qb + ((size_t)b * TLEN + qg) * HDIM + ks * 16 + hi * 8);

    bf16x8 kst[4], vst[4];

#define GLOAD(kv0_)                                                          \
    {                                                                        \
        _Pragma("unroll")                                                    \
        for (int it = 0; it < 4; ++it) {                                     \
            const int o = tid * 16 + it * 4096;                              \
            const int kr = o >> 8, kcb = o & 0xF0;                           \
            kst[it] = *(const bf16x8*)((const char*)Kb +                     \
                        (size_t)((kv0_) + kr) * 256 + kcb);                  \
            const int vr = o >> 7, vcb = o & 0x70;                           \
            vst[it] = *(const bf16x8*)((const char*)Vtb +                    \
                        (size_t)vr * (TLEN * 2) + (size_t)(kv0_) * 2 + vcb); \
        }                                                                    \
    }
#define SSTORE(bi_)                                                          \
    {                                                                        \
        _Pragma("unroll")                                                    \
        for (int it = 0; it < 4; ++it) {                                     \
            const int o = tid * 16 + it * 4096;                              \
            const int kr = o >> 8, kcb = o & 0xF0;                           \
            *(bf16x8*)((char*)Ks[bi_] + kr * 256 + (kcb ^ ((kr & 7) << 4))) = kst[it]; \
            const int vr = o >> 7, vcb = o & 0x70;                           \
            *(bf16x8*)((char*)Vs[bi_] + vr * 128 + (vcb ^ ((vr & 7) << 4))) = vst[it]; \
        }                                                                    \
    }

    GLOAD(kv_base);
    SSTORE(0);
    __syncthreads();

    f32x16 oacc[4];
#pragma unroll
    for (int i = 0; i < 4; ++i)
#pragma unroll
        for (int r = 0; r < 16; ++r) oacc[i][r] = 0.f;
    float m_r = -1e30f;     // finite sentinel: avoids inf-inf NaN paths
    float l_r = 0.f;

#pragma unroll 1
    for (int t = 0; t < NT; ++t) {
        const int bi = t & 1;
        if (t + 1 < NT) GLOAD(kv_base + 64 * (t + 1));

        const int kv0 = kv_base + 64 * t;
        if (kv0 <= q0w + 31) {          // tile non-empty for this wave
            // ---- QK^T: S^T[key][q], two 32-key blocks ----
            f32x16 s0, s1;
#pragma unroll
            for (int r = 0; r < 16; ++r) { s0[r] = 0.f; s1[r] = 0.f; }
#pragma unroll
            for (int ks = 0; ks < 8; ++ks) {
                const int col = ks * 32 + hi * 16;
                const int off0 = c5 * 256 + (col ^ ((c5 & 7) << 4));
                const int off1 = (32 + c5) * 256 + (col ^ ((c5 & 7) << 4));
                bf16x8 a0 = *(const bf16x8*)((char*)Ks[bi] + off0);
                bf16x8 a1 = *(const bf16x8*)((char*)Ks[bi] + off1);
                s0 = __builtin_amdgcn_mfma_f32_32x32x16_bf16(a0, qf[ks], s0, 0, 0, 0);
                s1 = __builtin_amdgcn_mfma_f32_32x32x16_bf16(a1, qf[ks], s1, 0, 0, 0);
            }

            // ---- causal mask (only near diagonal) ----
            if (kv0 + 63 > q0w) {
#pragma unroll
                for (int r = 0; r < 16; ++r) {
                    const int key0 = kv0 + (r & 3) + 8 * (r >> 2) + 4 * hi;
                    if (key0 > qg)      s0[r] = -INFINITY;
                    if (key0 + 32 > qg) s1[r] = -INFINITY;
                }
            }

            // ---- in-register online softmax (per q-row = per lane) ----
            float t8[8];
#pragma unroll
            for (int i = 0; i < 8; ++i)
                t8[i] = fmaxf(fmaxf(s0[2*i], s0[2*i+1]), fmaxf(s1[2*i], s1[2*i+1]));
            float smax = fmaxf(fmaxf(fmaxf(t8[0], t8[1]), fmaxf(t8[2], t8[3])),
                               fmaxf(fmaxf(t8[4], t8[5]), fmaxf(t8[6], t8[7])));
            smax = fmaxf(smax, __shfl_xor(smax, 32));

            const bool defer = __all(smax - m_r <= 8.0f);   // T13
            const float mnew = defer ? m_r : fmaxf(m_r, smax);
            if (!defer) {
                const float alpha = __expf(m_r - mnew);
                l_r *= alpha;
#pragma unroll
                for (int hb = 0; hb < 4; ++hb) oacc[hb] = oacc[hb] * alpha;
            }
            m_r = mnew;

#pragma unroll
            for (int r = 0; r < 16; ++r) {
                s0[r] = __expf(s0[r] - mnew);
                s1[r] = __expf(s1[r] - mnew);
            }
            float a8[8];
#pragma unroll
            for (int i = 0; i < 8; ++i)
                a8[i] = (s0[2*i] + s0[2*i+1]) + (s1[2*i] + s1[2*i+1]);
            float psum = ((a8[0] + a8[1]) + (a8[2] + a8[3])) +
                         ((a8[4] + a8[5]) + (a8[6] + a8[7]));
            psum += __shfl_xor(psum, 32);
            l_r += psum;

            // ---- pack P -> B-operand frags (P^T[k][q]), one shfl per slot ----
            bf16x8 pa[4];
#pragma unroll
            for (int kb2 = 0; kb2 < 2; ++kb2) {
#pragma unroll
                for (int par = 0; par < 2; ++par) {
                    const int e = par * 8;
                    float v0, v1, v2, v3, v4, v5, v6, v7;
                    if (kb2 == 0) {
                        v0=s0[e+0]; v1=s0[e+1]; v2=s0[e+2]; v3=s0[e+3];
                        v4=s0[e+4]; v5=s0[e+5]; v6=s0[e+6]; v7=s0[e+7];
                    } else {
                        v0=s1[e+0]; v1=s1[e+1]; v2=s1[e+2]; v3=s1[e+3];
                        v4=s1[e+4]; v5=s1[e+5]; v6=s1[e+6]; v7=s1[e+7];
                    }
                    const unsigned w0 = pkbf(v0, v1), w1 = pkbf(v2, v3);
                    const unsigned w2 = pkbf(v4, v5), w3 = pkbf(v6, v7);
                    const unsigned X0 = hi ? w0 : w2;   // send what partner needs
                    const unsigned X1 = hi ? w1 : w3;
                    const unsigned R0 = (unsigned)__shfl_xor((int)X0, 32);
                    const unsigned R1 = (unsigned)__shfl_xor((int)X1, 32);
                    union { unsigned w[4]; bf16x8 v; } uu;
                    uu.w[0] = hi ? R0 : w0;  uu.w[1] = hi ? R1 : w1;
                    uu.w[2] = hi ? w2 : R0;  uu.w[3] = hi ? w3 : R1;
                    pa[kb2 * 2 + par] = uu.v;
                }
            }

            // ---- PV: O[h][q] += V^T . P^T ----
#pragma unroll
            for (int hb = 0; hb < 4; ++hb) {
                const int row = hb * 32 + c5;
#pragma unroll
                for (int ks = 0; ks < 4; ++ks) {
                    const int off = row * 128 + ((ks * 32 + hi * 16) ^ ((row & 7) << 4));
                    bf16x8 va = *(const bf16x8*)((char*)Vs[bi] + off);
                    oacc[hb] = __builtin_amdgcn_mfma_f32_32x32x16_bf16(va, pa[ks], oacc[hb], 0, 0, 0);
                }
            }
        }

        if (t + 1 < NT) {
            SSTORE(bi ^ 1);
            __syncthreads();
        }
    }

    // ---- epilogue: O is [h=crow(r,hi)+32hb][q=c5]; transpose via LDS ----
    __syncthreads();                       // everyone done with Ks
    char* sl = (char*)Ks + wid * 8192;     // 8KB per wave: [32 q][128 h] bf16
#pragma unroll
    for (int hb = 0; hb < 4; ++hb)
#pragma unroll
        for (int rq = 0; rq < 4; ++rq) {
            u16x4 o4;
            o4[0] = f2bf(oacc[hb][rq * 4 + 0]);
            o4[1] = f2bf(oacc[hb][rq * 4 + 1]);
            o4[2] = f2bf(oacc[hb][rq * 4 + 2]);
            o4[3] = f2bf(oacc[hb][rq * 4 + 3]);
            const int off = c5 * 256 + ((hb * 64 + rq * 16 + hi * 8) ^ ((c5 & 7) << 4));
            *(u16x4*)(sl + off) = o4;
        }
    asm volatile("s_waitcnt lgkmcnt(0)" ::: "memory");
    __builtin_amdgcn_sched_barrier(0);

    const int qr = lane >> 1, hf = lane & 1;
    unsigned short* Og = Opart + (size_t)pidx * 128 * 128 +
                         (size_t)(wid * 32 + qr) * 128 + hf * 64;
#pragma unroll
    for (int i = 0; i < 8; ++i) {
        const int off = qr * 256 + ((hf * 128 + i * 16) ^ ((qr & 7) << 4));
        *(u16x8*)(Og + i * 8) = *(const u16x8*)(sl + off);
    }
    if (hi == 0) {
        mpart[(size_t)pidx * 128 + wid * 32 + c5] = m_r;
        lpart[(size_t)pidx * 128 + wid * 32 + c5] = l_r;
    }
#undef GLOAD
#undef SSTORE
}

// ---------------------------------------------------------------------------
// Kernel 2b: combine partials (unchanged).
// ---------------------------------------------------------------------------
__global__ __launch_bounds__(256) void attn_combine(
    const unsigned short* __restrict__ Opart, const float* __restrict__ mpart,
    const float* __restrict__ lpart, float* __restrict__ out)
{
    const int qc = blockIdx.x;
    const int b  = blockIdx.y;
    const int n  = (qc >> 1) + 1;
    const int base = b * 72 + part_offs(qc);
    const int t   = threadIdx.x;
    const int row = t >> 1;
    const int d0  = (t & 1) * 64;

    float M = -INFINITY;
    for (int p = 0; p < n; ++p)
        M = fmaxf(M, mpart[(size_t)(base + p) * 128 + row]);
    float L = 0.f;
    for (int p = 0; p < n; ++p)
        L += __expf(mpart[(size_t)(base + p) * 128 + row] - M) *
             lpart[(size_t)(base + p) * 128 + row];

    float acc[64];
#pragma unroll
    for (int i = 0; i < 64; ++i) acc[i] = 0.f;

    for (int p = 0; p < n; ++p) {
        const float w = __expf(mpart[(size_t)(base + p) * 128 + row] - M);
        const bf16x8* src = (const bf16x8*)(Opart +
            ((size_t)(base + p) * 128 + row) * 128 + d0);
#pragma unroll
        for (int j = 0; j < 8; ++j) {
            bf16x8 v = src[j];
#pragma unroll
            for (int e = 0; e < 8; ++e) {
                union { unsigned u; float f; } x;
                x.u = ((unsigned)(unsigned short)v[e]) << 16;
                acc[j * 8 + e] += w * x.f;
            }
        }
    }

    const float invL = 1.f / L;
    float4* dst = (float4*)(out + ((size_t)(b * TLEN + qc * 128 + row)) * 128 + d0);
#pragma unroll
    for (int i = 0; i < 16; ++i)
        dst[i] = make_float4(acc[4*i] * invL, acc[4*i+1] * invL,
                             acc[4*i+2] * invL, acc[4*i+3] * invL);
}

extern "C" void kernel_launch(void* const* d_in, const int* in_sizes, int n_in,
                              void* d_out, int out_size, void* d_ws, size_t ws_size,
                              hipStream_t stream)
{
    const float* x  = (const float*)d_in[0];
    const float* Wq = (const float*)d_in[1];
    const float* Wk = (const float*)d_in[2];
    const float* Wv = (const float*)d_in[3];
    float* outp = (float*)d_out;

    const size_t per = (size_t)BATCH * TLEN * HDIM;      // 4,194,304
    unsigned short* qb  = (unsigned short*)d_ws;
    unsigned short* kb  = qb + per;
    unsigned short* vtb = kb + per;
    unsigned short* wtb = vtb + per;                     // 384*1024 bf16
    unsigned short* Opart = wtb + 384 * 1024;            // 1152*128*128 bf16
    float* mpart = (float*)(Opart + (size_t)1152 * 128 * 128);
    float* lpart = mpart + (size_t)1152 * 128;

    dim3 gw(512, 3);
    pack_w<<<gw, 256, 0, stream>>>(Wq, Wk, Wv, wtb);

    qkv_mfma<<<768, 256, 0, stream>>>(x, wtb, qb, kb, vtb);

    dim3 g2(8, 16, BATCH);
    attn_partial<<<g2, 256, 0, stream>>>((const short*)qb, (const short*)kb,
                                         (const short*)vtb, Opart, mpart, lpart);

    dim3 g3(16, BATCH);
    attn_combine<<<g3, 256, 0, stream>>>(Opart, mpart, lpart, outp);
}